// Round 1
// 574.163 us; speedup vs baseline: 1.0192x; 1.0192x over previous
//
#include <hip/hip_runtime.h>

// Problem constants
// N=8, T_y=300, T_x=160, E=256, E/2=128, 3E=768
// d_out: [attn 8*300*160 = 384000][outputs 8*300*256 = 614400][hidden 2048]

typedef _Float16 f16x2 __attribute__((ext_vector_type(2)));

__device__ __forceinline__ float fexp2(float x) { return __builtin_amdgcn_exp2f(x); }
__device__ __forceinline__ float frcp(float x) { return __builtin_amdgcn_rcpf(x); }
// sigmoid(x) = 1/(1+2^(-x*log2 e))
__device__ __forceinline__ float fsig(float x) {
    return frcp(1.0f + fexp2(x * -1.4426950408889634f));
}
// tanh(y) = 1 - 2/(1+2^(y*2*log2 e)); saturates correctly at +-inf args
__device__ __forceinline__ float ftanh(float x) {
    return 1.0f - 2.0f * frcp(1.0f + fexp2(x * 2.8853900817779268f));
}

// dot2 on u32-packed f16x2 operands (bitcasts are free; avoids any element
// extract/pack ops in the hot loop).
__device__ __forceinline__ float fdot2u(unsigned a, unsigned b, float c) {
    union { unsigned u; f16x2 h; } x, y;
    x.u = a;
    y.u = b;
    return __builtin_amdgcn_fdot2(x.h, y.h, c, false);
}

// ---------------------------------------------------------------------------
// Kernel A: repack Whh (f32 [768][256]) into per-thread v_dot2 weight order.
// gru thread t (of 512): element e=t>>1, k-half odd=t&1. Thread owns ALL
// THREE gate rows of element e: rows {e, e+256, e+512} (rr=0,1,2) over
// k-range [odd*128, odd*128+128). Consumption order i = cp*12 + rr*4 + m,
// cp in [0,16): chunk of 8 f16 at k = 8*(cp+16*odd); m indexes the 4 f16x2
// of the chunk. wd layout [i*512 + t] so the one-time gru load is coalesced.
// ---------------------------------------------------------------------------
__global__ __launch_bounds__(256) void prep_wd(const float* __restrict__ Whh,
                                               unsigned* __restrict__ wd) {
    int gid = blockIdx.x * 256 + threadIdx.x;   // 0..98303 = 192*512
    int i = gid >> 9, t = gid & 511;
    int p = t >> 1, odd = t & 1;
    int cp = i / 12, rem = i - cp * 12;
    int rr = rem >> 2, m = rem & 3;
    int row = p + 256 * rr;                     // gate rows of element p
    int k = 8 * (cp + 16 * odd) + 2 * m;
    union { unsigned u; f16x2 h; } cv;
    cv.h[0] = (_Float16)Whh[(size_t)row * 256 + k];
    cv.h[1] = (_Float16)Whh[(size_t)row * 256 + k + 1];
    wd[i * 512 + t] = cv.u;
}

// ---------------------------------------------------------------------------
// Kernel B: generic f32 tiled GEMM  C[M,N] = X[M,K] @ Wt[N,K]^T
// mode 0: C f32 natural [row*N+col]
// mode 1: gi scatter: row=(b*300+t) -> store at (t*8+b)*768+col, bias folded
//         (bih+bhh for r,z gates; bih only for n gate)
// mode 2: C16 f16 natural
// BM=BN=64, BK=32, 256 threads, 4x4 per thread.
// ---------------------------------------------------------------------------
__global__ __launch_bounds__(256) void gemm_kernel(
    const float* __restrict__ X, const float* __restrict__ Wt,
    float* __restrict__ C, _Float16* __restrict__ C16,
    const float* __restrict__ bih, const float* __restrict__ bhh,
    int M, int N, int K, int mode) {
    __shared__ float Xs[32][65];
    __shared__ float Ws2[32][65];
    const int n0 = blockIdx.x * 64, m0 = blockIdx.y * 64;
    const int tid = threadIdx.x;
    const int tx = tid & 15, ty = tid >> 4;
    float acc[4][4] = {};
    for (int k0 = 0; k0 < K; k0 += 32) {
#pragma unroll
        for (int i = 0; i < 8; ++i) {
            int e = tid + i * 256;
            int kk = e & 31, m = e >> 5;
            int row = m0 + m;
            Xs[kk][m] = (row < M) ? X[(size_t)row * K + k0 + kk] : 0.0f;
            Ws2[kk][m] = Wt[(size_t)(n0 + m) * K + k0 + kk];
        }
        __syncthreads();
#pragma unroll
        for (int kk = 0; kk < 32; ++kk) {
            float a[4], b[4];
#pragma unroll
            for (int i = 0; i < 4; ++i) a[i] = Xs[kk][ty * 4 + i];
#pragma unroll
            for (int j = 0; j < 4; ++j) b[j] = Ws2[kk][tx * 4 + j];
#pragma unroll
            for (int i = 0; i < 4; ++i)
#pragma unroll
                for (int j = 0; j < 4; ++j) acc[i][j] += a[i] * b[j];
        }
        __syncthreads();
    }
#pragma unroll
    for (int i = 0; i < 4; ++i) {
        int row = m0 + ty * 4 + i;
        if (row >= M) continue;
#pragma unroll
        for (int j = 0; j < 4; ++j) {
            int col = n0 + tx * 4 + j;
            float val = acc[i][j];
            if (mode == 1) {
                int b = row / 300;
                int t = row - b * 300;
                val += (col < 512) ? (bih[col] + bhh[col]) : bih[col];
                C[(size_t)(t * 8 + b) * 768 + col] = val;
            } else if (mode == 2) {
                C16[(size_t)row * N + col] = (_Float16)val;
            } else {
                C[(size_t)row * N + col] = val;
            }
        }
    }
}

// ---------------------------------------------------------------------------
// Kernel C: GRU recurrence via v_dot2_f32_f16 (weights resident in VGPRs).
// 8 blocks (one per batch) x 512 threads. Lane PAIR (2e, 2e+1) owns element
// e: each lane computes the k-half of the three gate rows {e, e+256, e+512}
// (192 dot2/step/thread). 3x shfl_xor(.,1) combines the k-halves so BOTH
// lanes hold the full r/z/n sums, then the gate epilogue runs fully
// in-register (redundant per pair, but balanced across all 8 waves):
//   - NO ghbuf gather (was 512 LDS bank-conflict cycles/step + an LDS
//     round-trip of ~120cy latency on the serial path)
//   - ONE barrier/step instead of two
//   - stores split across the pair: odd lane -> outs, even -> hbuf/hid.
// h state stays f32 per lane; matvec input is f16 hbuf (same numerics as
// the 585us version).
// CRITICAL: cp loop must be FULLY unrolled so every w[...] index is a
// compile-time constant -> SROA keeps all 192 weights in registers. A
// partial unroll leaves runtime indices -> whole array spills to scratch
// (earlier session: VGPR_Count 44, 3.3 ms).
// Issue floor: 768x256 MACs / (256 MAC/cy/CU via dot2) = 768 cy/step.
// ---------------------------------------------------------------------------
__global__ __launch_bounds__(512, 2) void gru_kernel(
    const float* __restrict__ gi, const unsigned* __restrict__ wd,
    const float* __restrict__ h0, const float* __restrict__ bhh,
    float* __restrict__ outs, float* __restrict__ hid) {
    const int b = blockIdx.x;
    const int t = threadIdx.x;
    const int e = t >> 1;            // element 0..255
    const int codd = (t & 1) * 16;   // k-half chunk offset

    __shared__ __align__(16) _Float16 hbuf[2][256];

    // One-time resident weight load (coalesced): 192 regs/thread.
    unsigned w[192];
#pragma unroll
    for (int i = 0; i < 192; ++i) w[i] = wd[i * 512 + t];

    float h = h0[b * 256 + e];
    float bn = bhh[512 + e];         // bhh_n stays inside r*(.)
    if (!(t & 1)) hbuf[0][e] = (_Float16)h;
    const float* gp = gi + b * 768;
    float* op = outs + (size_t)b * 76800 + e;
    __syncthreads();

    for (int st = 0; st < 300; ++st) {
        // gi prefetch (independent of dot2 chain; scheduled early)
        const float* g = gp + (size_t)st * 6144;
        float gr = g[e], gz = g[e + 256], gn = g[e + 512];

        const _Float16* hb = hbuf[st & 1];
        float a00 = 0.f, a01 = 0.f, a10 = 0.f, a11 = 0.f, a20 = 0.f, a21 = 0.f;
#pragma unroll
        for (int cp = 0; cp < 16; ++cp) {
            uint4 hv = *(const uint4*)(hb + (cp + codd) * 8);  // 2-addr broadcast
            a00 = fdot2u(w[cp * 12 + 0], hv.x, a00);
            a01 = fdot2u(w[cp * 12 + 1], hv.y, a01);
            a00 = fdot2u(w[cp * 12 + 2], hv.z, a00);
            a01 = fdot2u(w[cp * 12 + 3], hv.w, a01);
            a10 = fdot2u(w[cp * 12 + 4], hv.x, a10);
            a11 = fdot2u(w[cp * 12 + 5], hv.y, a11);
            a10 = fdot2u(w[cp * 12 + 6], hv.z, a10);
            a11 = fdot2u(w[cp * 12 + 7], hv.w, a11);
            a20 = fdot2u(w[cp * 12 + 8], hv.x, a20);
            a21 = fdot2u(w[cp * 12 + 9], hv.y, a21);
            a20 = fdot2u(w[cp * 12 + 10], hv.z, a20);
            a21 = fdot2u(w[cp * 12 + 11], hv.w, a21);
        }
        // Combine k-halves across the lane pair; both lanes get full sums.
        float sr = a00 + a01;
        float sz = a10 + a11;
        float sn = a20 + a21;
        sr += __shfl_xor(sr, 1);
        sz += __shfl_xor(sz, 1);
        sn += __shfl_xor(sn, 1);

        // In-register gate epilogue (identical on both lanes of the pair).
        float r = fsig(gr + sr);
        float z = fsig(gz + sz);
        float n = ftanh(gn + r * (sn + bn));
        h = n + z * (h - n);

        if (t & 1)
            op[st * 256] = h;                       // odd lane: output store
        else
            hbuf[(st + 1) & 1][e] = (_Float16)h;    // even lane: next-h bcast
        __syncthreads();
    }
    if (!(t & 1)) hid[b * 256 + e] = h;
}

// ---------------------------------------------------------------------------
// Kernel D: scores + softmax. Block = (t-chunk of 10, batch). Threads 0..159
// each own one x. u16 for the whole batch (160x256 f16 = 80KB) is staged in
// LDS once per block with COALESCED global loads (the old per-thread
// row-major global reads had lane-stride 512B -> 64 cache lines per wave
// load). LDS row stride = 129 words so the per-x reads are conflict-free:
// bank = (129*tid + e2) % 32 = (tid + e2) % 32 -> 2 lanes/bank (free).
// ---------------------------------------------------------------------------
__global__ __launch_bounds__(256) void attn_kernel(
    const _Float16* __restrict__ u16, const float* __restrict__ wv,
    const float* __restrict__ v, float* __restrict__ attn) {
    const int tc = blockIdx.x, b = blockIdx.y;
    const int tid = threadIdx.x;
    __shared__ float wL[256], vL[256], sc[160], red[2];
    __shared__ unsigned uS[160 * 129];   // 82560B; f16-pairs, padded rows

    // Stage u16[b]: 160 rows x 128 words, coalesced (consecutive tid ->
    // consecutive words).
    const unsigned* ug = (const unsigned*)(u16 + (size_t)b * 160 * 256);
    for (int i = tid; i < 20480; i += 256) {
        int row = i >> 7, wi = i & 127;
        uS[row * 129 + wi] = ug[i];
    }
    vL[tid] = v[tid];

    for (int ti = 0; ti < 10; ++ti) {
        int t = tc * 10 + ti;
        wL[tid] = wv[(size_t)(b * 300 + t) * 256 + tid];
        __syncthreads();   // first iteration: also covers uS/vL staging
        float acc = 0.0f;
        if (tid < 160) {
            const unsigned* ur = uS + tid * 129;
#pragma unroll 8
            for (int e2 = 0; e2 < 128; ++e2) {
                union { unsigned uu; _Float16 hh[2]; } cv;
                cv.uu = ur[e2];
                int ee = e2 * 2;
                acc += vL[ee] * ftanh(wL[ee] + (float)cv.hh[0]);
                acc += vL[ee + 1] * ftanh(wL[ee + 1] + (float)cv.hh[1]);
            }
            sc[tid] = acc;
        }
        __syncthreads();
        if (tid < 64) {
            float m = -3.0e38f;
            for (int i = tid; i < 160; i += 64) m = fmaxf(m, sc[i]);
#pragma unroll
            for (int o = 32; o; o >>= 1) m = fmaxf(m, __shfl_xor(m, o));
            if (tid == 0) red[0] = m;
        }
        __syncthreads();
        float ee = 0.0f;
        if (tid < 160) {
            ee = fexp2((acc - red[0]) * 1.4426950408889634f);
            sc[tid] = ee;
        }
        __syncthreads();
        if (tid < 64) {
            float s = 0.0f;
            for (int i = tid; i < 160; i += 64) s += sc[i];
#pragma unroll
            for (int o = 32; o; o >>= 1) s += __shfl_xor(s, o);
            if (tid == 0) red[1] = s;
        }
        __syncthreads();
        if (tid < 160)
            attn[(size_t)(b * 300 + t) * 160 + tid] = ee * frcp(red[1]);
        __syncthreads();
    }
}

// ---------------------------------------------------------------------------
// ws layout (bytes):
//   [0, 7372800)        gi f32 [(t*8+b)*768 + col]           (live: K1b..gru)
//   [7372800, 7766016)  wd u32 dot2-weights [i*512+t]        (live: prep..gru)
//   [0, 655360)         u f16 [b*160+x][256]   (aliases dead gi, post-gru)
//   [655360, 3112960)   w f32 [b*300+t][256]   (aliases dead gi, post-gru)
// ---------------------------------------------------------------------------
extern "C" void kernel_launch(void* const* d_in, const int* in_sizes, int n_in,
                              void* d_out, int out_size, void* d_ws, size_t ws_size,
                              hipStream_t stream) {
    const float* inputs = (const float*)d_in[0];
    const float* memory = (const float*)d_in[1];
    const float* h0 = (const float*)d_in[2];
    const float* Wih = (const float*)d_in[3];
    const float* Whh = (const float*)d_in[4];
    const float* bih = (const float*)d_in[5];
    const float* bhh = (const float*)d_in[6];
    const float* Wm = (const float*)d_in[7];
    const float* Um = (const float*)d_in[8];
    const float* vv = (const float*)d_in[9];

    float* out = (float*)d_out;
    float* out_attn = out;              // 384000
    float* out_outputs = out + 384000;  // 614400
    float* out_hidden = out + 998400;   // 2048

    char* ws = (char*)d_ws;
    float* gi = (float*)ws;
    unsigned* wd = (unsigned*)(ws + 7372800);
    _Float16* u16 = (_Float16*)ws;
    float* wbuf = (float*)(ws + 655360);

    // Phase 1: weight repack + gi GEMM (bias-folded, scattered)
    prep_wd<<<384, 256, 0, stream>>>(Whh, wd);
    gemm_kernel<<<dim3(12, 38), 256, 0, stream>>>(inputs, Wih, gi, nullptr,
                                                  bih, bhh, 2400, 768, 128, 1);
    // Phase 2: sequential GRU (critical path, 8 CUs, weight-stationary dot2)
    gru_kernel<<<8, 512, 0, stream>>>(gi, wd, h0, bhh, out_outputs, out_hidden);
    // Phase 3: attention precompute + scores/softmax
    gemm_kernel<<<dim3(4, 20), 256, 0, stream>>>(memory, Um, nullptr, u16,
                                                 nullptr, nullptr, 1280, 256, 256, 2);
    gemm_kernel<<<dim3(4, 38), 256, 0, stream>>>(out_outputs, Wm, wbuf, nullptr,
                                                 nullptr, nullptr, 2400, 256, 256, 0);
    attn_kernel<<<dim3(30, 8), 256, 0, stream>>>(u16, wbuf, vv, out_attn);
}

// Round 2
// 568.449 us; speedup vs baseline: 1.0295x; 1.0101x over previous
//
#include <hip/hip_runtime.h>

// Problem constants
// N=8, T_y=300, T_x=160, E=256, E/2=128, 3E=768
// d_out: [attn 8*300*160 = 384000][outputs 8*300*256 = 614400][hidden 2048]

typedef _Float16 f16x2 __attribute__((ext_vector_type(2)));
typedef _Float16 f16x8 __attribute__((ext_vector_type(8)));
typedef float f32x4 __attribute__((ext_vector_type(4)));

__device__ __forceinline__ float fexp2(float x) { return __builtin_amdgcn_exp2f(x); }
__device__ __forceinline__ float frcp(float x) { return __builtin_amdgcn_rcpf(x); }
// sigmoid(x) = 1/(1+2^(-x*log2 e))
__device__ __forceinline__ float fsig(float x) {
    return frcp(1.0f + fexp2(x * -1.4426950408889634f));
}
// tanh(y) = 1 - 2/(1+2^(y*2*log2 e)); saturates correctly at +-inf args
__device__ __forceinline__ float ftanh(float x) {
    return 1.0f - 2.0f * frcp(1.0f + fexp2(x * 2.8853900817779268f));
}

// select component s (0..3) of a f32x4 with runtime s — pure cndmask tree,
// keeps everything in registers (rule #20: no runtime array indexing).
__device__ __forceinline__ float pick4(f32x4 v, int s) {
    float ab = (s & 1) ? v[1] : v[0];
    float cd = (s & 1) ? v[3] : v[2];
    return (s & 2) ? cd : ab;
}

// ---------------------------------------------------------------------------
// Kernel A: repack Whh (f32 [768][256]) into per-thread MFMA A-fragment order.
// gru thread t (of 512): wave w=t>>6, lane l=t&63. Wave w owns M-tiles
// (gate g, half m2): rows 256g + 32w + 16*m2 + (l&15). A-frag for
// mfma_f32_16x16x32_f16: lane l holds A[row=l&15][k=(l>>4)*8 + i], i=0..7,
// packed as 4 dwords (dword j = elements 2j, 2j+1). Fragment index
// fi = (g*2+m2)*8 + ks (ks = K-step, k base 32*ks); dword index i = fi*4+j.
// wd layout [i*512 + t] so the one-time gru load is coalesced.
// ---------------------------------------------------------------------------
__global__ __launch_bounds__(256) void prep_wd(const float* __restrict__ Whh,
                                               unsigned* __restrict__ wd) {
    int gid = blockIdx.x * 256 + threadIdx.x;   // 0..98303 = 192*512
    int i = gid >> 9, t = gid & 511;
    int fi = i >> 2, j = i & 3;
    int g = fi >> 4, m2 = (fi >> 3) & 1, ks = fi & 7;
    int w = t >> 6, l = t & 63;
    int row = 256 * g + 32 * w + 16 * m2 + (l & 15);
    int k = 32 * ks + 8 * (l >> 4) + 2 * j;
    union { unsigned u; f16x2 h; } cv;
    cv.h[0] = (_Float16)Whh[(size_t)row * 256 + k];
    cv.h[1] = (_Float16)Whh[(size_t)row * 256 + k + 1];
    wd[i * 512 + t] = cv.u;
}

// ---------------------------------------------------------------------------
// Kernel B: generic f32 tiled GEMM  C[M,N] = X[M,K] @ Wt[N,K]^T
// mode 0: C f32 natural [row*N+col]
// mode 1: gi scatter: row=(b*300+t) -> store at (t*8+b)*768+col, bias folded
//         (bih+bhh for r,z gates; bih only for n gate)
// mode 2: C16 f16 natural
// BM=BN=64, BK=32, 256 threads, 4x4 per thread.
// ---------------------------------------------------------------------------
__global__ __launch_bounds__(256) void gemm_kernel(
    const float* __restrict__ X, const float* __restrict__ Wt,
    float* __restrict__ C, _Float16* __restrict__ C16,
    const float* __restrict__ bih, const float* __restrict__ bhh,
    int M, int N, int K, int mode) {
    __shared__ float Xs[32][65];
    __shared__ float Ws2[32][65];
    const int n0 = blockIdx.x * 64, m0 = blockIdx.y * 64;
    const int tid = threadIdx.x;
    const int tx = tid & 15, ty = tid >> 4;
    float acc[4][4] = {};
    for (int k0 = 0; k0 < K; k0 += 32) {
#pragma unroll
        for (int i = 0; i < 8; ++i) {
            int e = tid + i * 256;
            int kk = e & 31, m = e >> 5;
            int row = m0 + m;
            Xs[kk][m] = (row < M) ? X[(size_t)row * K + k0 + kk] : 0.0f;
            Ws2[kk][m] = Wt[(size_t)(n0 + m) * K + k0 + kk];
        }
        __syncthreads();
#pragma unroll
        for (int kk = 0; kk < 32; ++kk) {
            float a[4], b[4];
#pragma unroll
            for (int i = 0; i < 4; ++i) a[i] = Xs[kk][ty * 4 + i];
#pragma unroll
            for (int j = 0; j < 4; ++j) b[j] = Ws2[kk][tx * 4 + j];
#pragma unroll
            for (int i = 0; i < 4; ++i)
#pragma unroll
                for (int j = 0; j < 4; ++j) acc[i][j] += a[i] * b[j];
        }
        __syncthreads();
    }
#pragma unroll
    for (int i = 0; i < 4; ++i) {
        int row = m0 + ty * 4 + i;
        if (row >= M) continue;
#pragma unroll
        for (int j = 0; j < 4; ++j) {
            int col = n0 + tx * 4 + j;
            float val = acc[i][j];
            if (mode == 1) {
                int b = row / 300;
                int t = row - b * 300;
                val += (col < 512) ? (bih[col] + bhh[col]) : bih[col];
                C[(size_t)(t * 8 + b) * 768 + col] = val;
            } else if (mode == 2) {
                C16[(size_t)row * N + col] = (_Float16)val;
            } else {
                C[(size_t)row * N + col] = val;
            }
        }
    }
}

// ---------------------------------------------------------------------------
// Kernel C: GRU recurrence on the MATRIX pipe (v_mfma_f32_16x16x32_f16).
// Rationale: the dot2 version was stuck at ~2633 cy/step with active-CU
// VALUBusy ~70% -- ~2x the dot2 issue floor (suspected v_accvgpr_read per
// dot2 for AGPR-resident weights, or half-rate dot2). MFMA reads A/B
// operands natively from AGPRs (unified file), so the 192 weight registers
// cost zero moves, and the matrix pipe does the matvec in
// 48 MFMA/wave ~ 466 cy/SIMD issue vs 768+ for dot2.
//
// 8 blocks (one per batch) x 512 threads (8 waves, 2/SIMD). Wave w owns
// gate-colocated M-tiles {r,z,n} x {2w,2w+1}: rows 256g+32w+16*m2+(l&15).
// B-operand: h (f16, LDS) REPLICATED across all 16 columns -- lane l reads
// h16[32*ks + 8*(l>>4) .. +8] so B[k][n]=h[k] for all n. Consequence:
// D[m][n]=y[m] for all n, i.e. every lane holds the full y for its 4-row
// group (row = 4*(l>>4)+reg, col replicated). Epilogue is fully in-register:
// each lane selects ONE element e via (sel=l&7): m2=sel>>2, reg=sel&3,
// e = 32w + 16*m2 + 4*(l>>4) + reg  (each e covered by 2 lanes, hi=l>>3&1;
// hi=0 writes hbuf/hid, hi=1 writes outs). No ghbuf, no shfl, ONE
// barrier/step.
// CRITICAL: all loops fully unrolled so wf[] indices are compile-time
// constants (rule #20: runtime-indexed arrays go to scratch).
// ---------------------------------------------------------------------------
__global__ __launch_bounds__(512, 2) void gru_kernel(
    const float* __restrict__ gi, const unsigned* __restrict__ wd,
    const float* __restrict__ h0, const float* __restrict__ bhh,
    float* __restrict__ outs, float* __restrict__ hid) {
    const int b = blockIdx.x;
    const int t = threadIdx.x;
    const int w = t >> 6, l = t & 63;
    const int grp = l >> 4;          // D row group / B k-chunk group
    const int sel = l & 7;           // element select within the wave's rows
    const int hi = (l >> 3) & 1;     // duplicate flag (2 lanes per element)
    const int m2s = sel >> 2, rsel = sel & 3;
    const int e = 32 * w + 16 * m2s + 4 * grp + rsel;

    __shared__ __align__(16) _Float16 hbuf[2][256];

    // One-time weight load into 48 A-fragments (192 regs; coalesced).
    f16x8 wf[48];
#pragma unroll
    for (int fi = 0; fi < 48; ++fi) {
        union { unsigned u[4]; f16x8 v; } cv;
#pragma unroll
        for (int j = 0; j < 4; ++j) cv.u[j] = wd[(fi * 4 + j) * 512 + t];
        wf[fi] = cv.v;
    }

    float h = h0[b * 256 + e];
    float bn = bhh[512 + e];         // bhh_n stays inside r*(.)
    if (!hi) hbuf[0][e] = (_Float16)h;
    const float* gp = gi + b * 768;
    float* op = outs + (size_t)b * 76800 + e;
    __syncthreads();

    for (int st = 0; st < 300; ++st) {
        // gi prefetch (independent of MFMA chain; scheduled early)
        const float* g = gp + (size_t)st * 6144;
        float gr = g[e], gz = g[e + 256], gn = g[e + 512];

        const _Float16* hb = hbuf[st & 1];
        f32x4 aR0 = {0.f, 0.f, 0.f, 0.f}, aR1 = {0.f, 0.f, 0.f, 0.f};
        f32x4 aZ0 = {0.f, 0.f, 0.f, 0.f}, aZ1 = {0.f, 0.f, 0.f, 0.f};
        f32x4 aN0 = {0.f, 0.f, 0.f, 0.f}, aN1 = {0.f, 0.f, 0.f, 0.f};
#pragma unroll
        for (int ks = 0; ks < 8; ++ks) {
            f16x8 hv = *(const f16x8*)(hb + 32 * ks + 8 * grp);  // bcast-4
            aR0 = __builtin_amdgcn_mfma_f32_16x16x32_f16(wf[0 * 8 + ks], hv, aR0, 0, 0, 0);
            aR1 = __builtin_amdgcn_mfma_f32_16x16x32_f16(wf[1 * 8 + ks], hv, aR1, 0, 0, 0);
            aZ0 = __builtin_amdgcn_mfma_f32_16x16x32_f16(wf[2 * 8 + ks], hv, aZ0, 0, 0, 0);
            aZ1 = __builtin_amdgcn_mfma_f32_16x16x32_f16(wf[3 * 8 + ks], hv, aZ1, 0, 0, 0);
            aN0 = __builtin_amdgcn_mfma_f32_16x16x32_f16(wf[4 * 8 + ks], hv, aN0, 0, 0, 0);
            aN1 = __builtin_amdgcn_mfma_f32_16x16x32_f16(wf[5 * 8 + ks], hv, aN1, 0, 0, 0);
        }
        // Select this lane's element sums from the replicated fragments.
        f32x4 vR = m2s ? aR1 : aR0;
        f32x4 vZ = m2s ? aZ1 : aZ0;
        f32x4 vN = m2s ? aN1 : aN0;
        float sr = pick4(vR, rsel);
        float sz = pick4(vZ, rsel);
        float sn = pick4(vN, rsel);

        // In-register gate epilogue (each element computed by its 2 lanes).
        float r = fsig(gr + sr);
        float z = fsig(gz + sz);
        float n = ftanh(gn + r * (sn + bn));
        h = n + z * (h - n);

        if (hi)
            op[st * 256] = h;                       // outs store
        else
            hbuf[(st + 1) & 1][e] = (_Float16)h;    // next-h broadcast
        __syncthreads();
    }
    if (!hi) hid[b * 256 + e] = h;
}

// ---------------------------------------------------------------------------
// Kernel D: scores + softmax. Block = (t-chunk of 10, batch). Threads 0..159
// each own one x. u16 for the whole batch (160x256 f16 = 80KB) is staged in
// LDS once per block with COALESCED global loads. LDS row stride = 129 words
// so the per-x reads are conflict-free.
// ---------------------------------------------------------------------------
__global__ __launch_bounds__(256) void attn_kernel(
    const _Float16* __restrict__ u16, const float* __restrict__ wv,
    const float* __restrict__ v, float* __restrict__ attn) {
    const int tc = blockIdx.x, b = blockIdx.y;
    const int tid = threadIdx.x;
    __shared__ float wL[256], vL[256], sc[160], red[2];
    __shared__ unsigned uS[160 * 129];   // 82560B; f16-pairs, padded rows

    const unsigned* ug = (const unsigned*)(u16 + (size_t)b * 160 * 256);
    for (int i = tid; i < 20480; i += 256) {
        int row = i >> 7, wi = i & 127;
        uS[row * 129 + wi] = ug[i];
    }
    vL[tid] = v[tid];

    for (int ti = 0; ti < 10; ++ti) {
        int t = tc * 10 + ti;
        wL[tid] = wv[(size_t)(b * 300 + t) * 256 + tid];
        __syncthreads();   // first iteration: also covers uS/vL staging
        float acc = 0.0f;
        if (tid < 160) {
            const unsigned* ur = uS + tid * 129;
#pragma unroll 8
            for (int e2 = 0; e2 < 128; ++e2) {
                union { unsigned uu; _Float16 hh[2]; } cv;
                cv.uu = ur[e2];
                int ee = e2 * 2;
                acc += vL[ee] * ftanh(wL[ee] + (float)cv.hh[0]);
                acc += vL[ee + 1] * ftanh(wL[ee + 1] + (float)cv.hh[1]);
            }
            sc[tid] = acc;
        }
        __syncthreads();
        if (tid < 64) {
            float m = -3.0e38f;
            for (int i = tid; i < 160; i += 64) m = fmaxf(m, sc[i]);
#pragma unroll
            for (int o = 32; o; o >>= 1) m = fmaxf(m, __shfl_xor(m, o));
            if (tid == 0) red[0] = m;
        }
        __syncthreads();
        float ee = 0.0f;
        if (tid < 160) {
            ee = fexp2((acc - red[0]) * 1.4426950408889634f);
            sc[tid] = ee;
        }
        __syncthreads();
        if (tid < 64) {
            float s = 0.0f;
            for (int i = tid; i < 160; i += 64) s += sc[i];
#pragma unroll
            for (int o = 32; o; o >>= 1) s += __shfl_xor(s, o);
            if (tid == 0) red[1] = s;
        }
        __syncthreads();
        if (tid < 160)
            attn[(size_t)(b * 300 + t) * 160 + tid] = ee * frcp(red[1]);
        __syncthreads();
    }
}

// ---------------------------------------------------------------------------
// ws layout (bytes):
//   [0, 7372800)        gi f32 [(t*8+b)*768 + col]           (live: K1b..gru)
//   [7372800, 7766016)  wd u32 mfma A-frags [i*512+t]        (live: prep..gru)
//   [0, 655360)         u f16 [b*160+x][256]   (aliases dead gi, post-gru)
//   [655360, 3112960)   w f32 [b*300+t][256]   (aliases dead gi, post-gru)
// ---------------------------------------------------------------------------
extern "C" void kernel_launch(void* const* d_in, const int* in_sizes, int n_in,
                              void* d_out, int out_size, void* d_ws, size_t ws_size,
                              hipStream_t stream) {
    const float* inputs = (const float*)d_in[0];
    const float* memory = (const float*)d_in[1];
    const float* h0 = (const float*)d_in[2];
    const float* Wih = (const float*)d_in[3];
    const float* Whh = (const float*)d_in[4];
    const float* bih = (const float*)d_in[5];
    const float* bhh = (const float*)d_in[6];
    const float* Wm = (const float*)d_in[7];
    const float* Um = (const float*)d_in[8];
    const float* vv = (const float*)d_in[9];

    float* out = (float*)d_out;
    float* out_attn = out;              // 384000
    float* out_outputs = out + 384000;  // 614400
    float* out_hidden = out + 998400;   // 2048

    char* ws = (char*)d_ws;
    float* gi = (float*)ws;
    unsigned* wd = (unsigned*)(ws + 7372800);
    _Float16* u16 = (_Float16*)ws;
    float* wbuf = (float*)(ws + 655360);

    // Phase 1: weight repack + gi GEMM (bias-folded, scattered)
    prep_wd<<<384, 256, 0, stream>>>(Whh, wd);
    gemm_kernel<<<dim3(12, 38), 256, 0, stream>>>(inputs, Wih, gi, nullptr,
                                                  bih, bhh, 2400, 768, 128, 1);
    // Phase 2: sequential GRU (critical path, 8 CUs, weight-stationary MFMA)
    gru_kernel<<<8, 512, 0, stream>>>(gi, wd, h0, bhh, out_outputs, out_hidden);
    // Phase 3: attention precompute + scores/softmax
    gemm_kernel<<<dim3(4, 20), 256, 0, stream>>>(memory, Um, nullptr, u16,
                                                 nullptr, nullptr, 1280, 256, 256, 2);
    gemm_kernel<<<dim3(4, 38), 256, 0, stream>>>(out_outputs, Wm, wbuf, nullptr,
                                                 nullptr, nullptr, 2400, 256, 256, 0);
    attn_kernel<<<dim3(30, 8), 256, 0, stream>>>(u16, wbuf, vv, out_attn);
}

// Round 5
// 531.114 us; speedup vs baseline: 1.1019x; 1.0703x over previous
//
#include <hip/hip_runtime.h>

// Problem constants
// N=8, T_y=300, T_x=160, E=256, E/2=128, 3E=768
// d_out: [attn 8*300*160 = 384000][outputs 8*300*256 = 614400][hidden 2048]

typedef _Float16 f16x2 __attribute__((ext_vector_type(2)));
typedef _Float16 f16x8 __attribute__((ext_vector_type(8)));
typedef float f32x4 __attribute__((ext_vector_type(4)));

__device__ __forceinline__ float fexp2(float x) { return __builtin_amdgcn_exp2f(x); }
__device__ __forceinline__ float frcp(float x) { return __builtin_amdgcn_rcpf(x); }
// sigmoid(x) = 1/(1+2^(-x*log2 e))
__device__ __forceinline__ float fsig(float x) {
    return frcp(1.0f + fexp2(x * -1.4426950408889634f));
}
// tanh(y) = 1 - 2/(1+2^(y*2*log2 e)); saturates correctly at +-inf args
__device__ __forceinline__ float ftanh(float x) {
    return 1.0f - 2.0f * frcp(1.0f + fexp2(x * 2.8853900817779268f));
}

// select component s (0..3) of a f32x4 with runtime s — pure cndmask tree,
// keeps everything in registers (rule #20: no runtime array indexing).
__device__ __forceinline__ float pick4(f32x4 v, int s) {
    float ab = (s & 1) ? v[1] : v[0];
    float cd = (s & 1) ? v[3] : v[2];
    return (s & 2) ? cd : ab;
}

// ---------------------------------------------------------------------------
// Kernel A: repack Whh (f32 [768][256]) into per-thread MFMA A-fragment order.
// gru thread t (of 512): wave w=t>>6, lane l=t&63. Wave w owns M-tiles
// (gate g, half m2): rows 256g + 32w + 16*m2 + (l&15). A-frag for
// mfma_f32_16x16x32_f16: lane l holds A[row=l&15][k=(l>>4)*8 + i], i=0..7,
// packed as 4 dwords (dword j = elements 2j, 2j+1). Fragment index
// fi = (g*2+m2)*8 + ks (ks = K-step, k base 32*ks); dword index i = fi*4+j.
// wd layout [i*512 + t] so the one-time gru load is coalesced.
// (Layout verified by round-2 pass @ absmax 0.0039.)
// ---------------------------------------------------------------------------
__global__ __launch_bounds__(256) void prep_wd(const float* __restrict__ Whh,
                                               unsigned* __restrict__ wd) {
    int gid = blockIdx.x * 256 + threadIdx.x;   // 0..98303 = 192*512
    int i = gid >> 9, t = gid & 511;
    int fi = i >> 2, j = i & 3;
    int g = fi >> 4, m2 = (fi >> 3) & 1, ks = fi & 7;
    int w = t >> 6, l = t & 63;
    int row = 256 * g + 32 * w + 16 * m2 + (l & 15);
    int k = 32 * ks + 8 * (l >> 4) + 2 * j;
    union { unsigned u; f16x2 h; } cv;
    cv.h[0] = (_Float16)Whh[(size_t)row * 256 + k];
    cv.h[1] = (_Float16)Whh[(size_t)row * 256 + k + 1];
    wd[i * 512 + t] = cv.u;
}

// ---------------------------------------------------------------------------
// Kernel B: generic f32 tiled GEMM  C[M,N] = X[M,K] @ Wt[N,K]^T
// mode 0: C f32 natural [row*N+col]
// mode 1: gi scatter: row=(b*300+t) -> store at (t*8+b)*768+col, bias folded
//         (bih+bhh for r,z gates; bih only for n gate)
// mode 2: C16 f16 natural
// BM=BN=64, BK=32, 256 threads, 4x4 per thread.
// ---------------------------------------------------------------------------
__global__ __launch_bounds__(256) void gemm_kernel(
    const float* __restrict__ X, const float* __restrict__ Wt,
    float* __restrict__ C, _Float16* __restrict__ C16,
    const float* __restrict__ bih, const float* __restrict__ bhh,
    int M, int N, int K, int mode) {
    __shared__ float Xs[32][65];
    __shared__ float Ws2[32][65];
    const int n0 = blockIdx.x * 64, m0 = blockIdx.y * 64;
    const int tid = threadIdx.x;
    const int tx = tid & 15, ty = tid >> 4;
    float acc[4][4] = {};
    for (int k0 = 0; k0 < K; k0 += 32) {
#pragma unroll
        for (int i = 0; i < 8; ++i) {
            int e = tid + i * 256;
            int kk = e & 31, m = e >> 5;
            int row = m0 + m;
            Xs[kk][m] = (row < M) ? X[(size_t)row * K + k0 + kk] : 0.0f;
            Ws2[kk][m] = Wt[(size_t)(n0 + m) * K + k0 + kk];
        }
        __syncthreads();
#pragma unroll
        for (int kk = 0; kk < 32; ++kk) {
            float a[4], b[4];
#pragma unroll
            for (int i = 0; i < 4; ++i) a[i] = Xs[kk][ty * 4 + i];
#pragma unroll
            for (int j = 0; j < 4; ++j) b[j] = Ws2[kk][tx * 4 + j];
#pragma unroll
            for (int i = 0; i < 4; ++i)
#pragma unroll
                for (int j = 0; j < 4; ++j) acc[i][j] += a[i] * b[j];
        }
        __syncthreads();
    }
#pragma unroll
    for (int i = 0; i < 4; ++i) {
        int row = m0 + ty * 4 + i;
        if (row >= M) continue;
#pragma unroll
        for (int j = 0; j < 4; ++j) {
            int col = n0 + tx * 4 + j;
            float val = acc[i][j];
            if (mode == 1) {
                int b = row / 300;
                int t = row - b * 300;
                val += (col < 512) ? (bih[col] + bhh[col]) : bih[col];
                C[(size_t)(t * 8 + b) * 768 + col] = val;
            } else if (mode == 2) {
                C16[(size_t)row * N + col] = (_Float16)val;
            } else {
                C[(size_t)row * N + col] = val;
            }
        }
    }
}

// ---------------------------------------------------------------------------
// Kernel C: GRU recurrence on the MATRIX pipe (v_mfma_f32_16x16x32_f16).
// 8 blocks (one per batch) x 512 threads (8 waves, 2/SIMD). Wave w owns
// gate-colocated M-tiles {r,z,n} x {2w,2w+1}. B-operand: h (f16, LDS)
// replicated across all 16 columns, so D is replicated and each lane holds
// full y for its rows -> in-register epilogue, one barrier/step.
//
// Round-5 (counter-driven, after two failed inline-asm-MFMA rounds):
//  1. INTRINSIC MFMA restored — the r3/r4 inline-asm path has unfixable-at-
//     source hazard holes (MFMA→VALU WAW on accumulator re-init is not
//     blocked by a "memory" clobber; r4's 0.139 error). Intrinsics get
//     compiler-inserted wait states. Numerics = round-2 (passed, 0.0039).
//  2. lgkmcnt-only fused barrier (asm + "memory" clobber — validated in r4:
//     the r3 NaN from the fence-less builtin barrier is gone). The outs
//     store ack and gi loads no longer drain at each step barrier.
//  3. gi prefetched ONE STEP AHEAD into registers: r2's step time (~2560cy)
//     ≈ gi HBM latency (~900cy, streamed-once data) + compute, serialized
//     by __syncthreads' vmcnt(0). Prefetching st+1 during st hides it.
// CRITICAL: all loops fully unrolled so wf[] indices are compile-time
// constants (rule #20: runtime-indexed arrays go to scratch).
// ---------------------------------------------------------------------------
__global__ __launch_bounds__(512, 1) void gru_kernel(
    const float* __restrict__ gi, const unsigned* __restrict__ wd,
    const float* __restrict__ h0, const float* __restrict__ bhh,
    float* __restrict__ outs, float* __restrict__ hid) {
    const int b = blockIdx.x;
    const int t = threadIdx.x;
    const int w = t >> 6, l = t & 63;
    const int grp = l >> 4;          // D row group / B k-chunk group
    const int sel = l & 7;           // element select within the wave's rows
    const int hi = (l >> 3) & 1;     // duplicate flag (2 lanes per element)
    const int m2s = sel >> 2, rsel = sel & 3;
    const int e = 32 * w + 16 * m2s + 4 * grp + rsel;

    __shared__ __align__(16) _Float16 hbuf[2][256];

    // One-time weight load into 48 A-fragments (192 regs; coalesced).
    f16x8 wf[48];
#pragma unroll
    for (int fi = 0; fi < 48; ++fi) {
        union { unsigned u[4]; f16x8 v; } cv;
#pragma unroll
        for (int j = 0; j < 4; ++j) cv.u[j] = wd[(fi * 4 + j) * 512 + t];
        wf[fi] = cv.v;
    }

    float h = h0[b * 256 + e];
    float bn = bhh[512 + e];         // bhh_n stays inside r*(.)
    if (!hi) hbuf[0][e] = (_Float16)h;
    const float* gp = gi + b * 768;
    float* op = outs + (size_t)b * 76800 + e;

    // Prime the gi pipeline: step-0 values loaded before the loop.
    float gr = gp[e], gz = gp[e + 256], gn = gp[e + 512];
    __syncthreads();

    for (int st = 0; st < 300; ++st) {
        // Prefetch NEXT step's gi (issued here, consumed next iteration —
        // one full step of MFMA work hides the HBM/L2 latency).
        int stn = (st < 299) ? st + 1 : st;
        const float* g = gp + (size_t)stn * 6144;
        float grn = g[e], gzn = g[e + 256], gnn = g[e + 512];

        const _Float16* hb = hbuf[st & 1];
        // All 8 B-fragments up front; compiler pipelines the ds_reads.
        f16x8 hv0 = *(const f16x8*)(hb + 0 * 32 + 8 * grp);
        f16x8 hv1 = *(const f16x8*)(hb + 1 * 32 + 8 * grp);
        f16x8 hv2 = *(const f16x8*)(hb + 2 * 32 + 8 * grp);
        f16x8 hv3 = *(const f16x8*)(hb + 3 * 32 + 8 * grp);
        f16x8 hv4 = *(const f16x8*)(hb + 4 * 32 + 8 * grp);
        f16x8 hv5 = *(const f16x8*)(hb + 5 * 32 + 8 * grp);
        f16x8 hv6 = *(const f16x8*)(hb + 6 * 32 + 8 * grp);
        f16x8 hv7 = *(const f16x8*)(hb + 7 * 32 + 8 * grp);

        f32x4 aR0 = {0.f, 0.f, 0.f, 0.f}, aR1 = {0.f, 0.f, 0.f, 0.f};
        f32x4 aZ0 = {0.f, 0.f, 0.f, 0.f}, aZ1 = {0.f, 0.f, 0.f, 0.f};
        f32x4 aN0 = {0.f, 0.f, 0.f, 0.f}, aN1 = {0.f, 0.f, 0.f, 0.f};
#define KSTEP(ks, hv)                                                        \
        aR0 = __builtin_amdgcn_mfma_f32_16x16x32_f16(wf[0 * 8 + ks], hv, aR0, 0, 0, 0); \
        aR1 = __builtin_amdgcn_mfma_f32_16x16x32_f16(wf[1 * 8 + ks], hv, aR1, 0, 0, 0); \
        aZ0 = __builtin_amdgcn_mfma_f32_16x16x32_f16(wf[2 * 8 + ks], hv, aZ0, 0, 0, 0); \
        aZ1 = __builtin_amdgcn_mfma_f32_16x16x32_f16(wf[3 * 8 + ks], hv, aZ1, 0, 0, 0); \
        aN0 = __builtin_amdgcn_mfma_f32_16x16x32_f16(wf[4 * 8 + ks], hv, aN0, 0, 0, 0); \
        aN1 = __builtin_amdgcn_mfma_f32_16x16x32_f16(wf[5 * 8 + ks], hv, aN1, 0, 0, 0);
        KSTEP(0, hv0) KSTEP(1, hv1) KSTEP(2, hv2) KSTEP(3, hv3)
        KSTEP(4, hv4) KSTEP(5, hv5) KSTEP(6, hv6) KSTEP(7, hv7)
#undef KSTEP

        // Select this lane's element sums from the replicated fragments.
        f32x4 vR = m2s ? aR1 : aR0;
        f32x4 vZ = m2s ? aZ1 : aZ0;
        f32x4 vN = m2s ? aN1 : aN0;
        float sr = pick4(vR, rsel);
        float sz = pick4(vZ, rsel);
        float sn = pick4(vN, rsel);

        // In-register gate epilogue (each element computed by its 2 lanes).
        float r = fsig(gr + sr);
        float z = fsig(gz + sz);
        float n = ftanh(gn + r * (sn + bn));
        h = n + z * (h - n);

        // Rotate the gi pipeline.
        gr = grn; gz = gzn; gn = gnn;

        if (hi)
            op[st * 256] = h;                       // outs store (no drain)
        else
            hbuf[(st + 1) & 1][e] = (_Float16)h;    // next-h broadcast
        // Fused waitcnt+barrier WITH memory clobber: compiler-level fence in
        // both directions; hardware waits only on LDS (no vmcnt drain — the
        // outs stores and gi prefetch loads stay in flight).
        asm volatile("s_waitcnt lgkmcnt(0)\n\ts_barrier" ::: "memory");
    }
    if (!hi) hid[b * 256 + e] = h;
}

// ---------------------------------------------------------------------------
// Kernel D: scores + softmax. Block = (t-chunk of 10, batch). Threads 0..159
// each own one x. u16 for the whole batch (160x256 f16 = 80KB) is staged in
// LDS once per block with COALESCED global loads. LDS row stride = 129 words
// so the per-x reads are conflict-free.
// ---------------------------------------------------------------------------
__global__ __launch_bounds__(256) void attn_kernel(
    const _Float16* __restrict__ u16, const float* __restrict__ wv,
    const float* __restrict__ v, float* __restrict__ attn) {
    const int tc = blockIdx.x, b = blockIdx.y;
    const int tid = threadIdx.x;
    __shared__ float wL[256], vL[256], sc[160], red[2];
    __shared__ unsigned uS[160 * 129];   // 82560B; f16-pairs, padded rows

    const unsigned* ug = (const unsigned*)(u16 + (size_t)b * 160 * 256);
    for (int i = tid; i < 20480; i += 256) {
        int row = i >> 7, wi = i & 127;
        uS[row * 129 + wi] = ug[i];
    }
    vL[tid] = v[tid];

    for (int ti = 0; ti < 10; ++ti) {
        int t = tc * 10 + ti;
        wL[tid] = wv[(size_t)(b * 300 + t) * 256 + tid];
        __syncthreads();   // first iteration: also covers uS/vL staging
        float acc = 0.0f;
        if (tid < 160) {
            const unsigned* ur = uS + tid * 129;
#pragma unroll 8
            for (int e2 = 0; e2 < 128; ++e2) {
                union { unsigned uu; _Float16 hh[2]; } cv;
                cv.uu = ur[e2];
                int ee = e2 * 2;
                acc += vL[ee] * ftanh(wL[ee] + (float)cv.hh[0]);
                acc += vL[ee + 1] * ftanh(wL[ee + 1] + (float)cv.hh[1]);
            }
            sc[tid] = acc;
        }
        __syncthreads();
        if (tid < 64) {
            float m = -3.0e38f;
            for (int i = tid; i < 160; i += 64) m = fmaxf(m, sc[i]);
#pragma unroll
            for (int o = 32; o; o >>= 1) m = fmaxf(m, __shfl_xor(m, o));
            if (tid == 0) red[0] = m;
        }
        __syncthreads();
        float ee = 0.0f;
        if (tid < 160) {
            ee = fexp2((acc - red[0]) * 1.4426950408889634f);
            sc[tid] = ee;
        }
        __syncthreads();
        if (tid < 64) {
            float s = 0.0f;
            for (int i = tid; i < 160; i += 64) s += sc[i];
#pragma unroll
            for (int o = 32; o; o >>= 1) s += __shfl_xor(s, o);
            if (tid == 0) red[1] = s;
        }
        __syncthreads();
        if (tid < 160)
            attn[(size_t)(b * 300 + t) * 160 + tid] = ee * frcp(red[1]);
        __syncthreads();
    }
}

// ---------------------------------------------------------------------------
// ws layout (bytes):
//   [0, 7372800)        gi f32 [(t*8+b)*768 + col]           (live: K1b..gru)
//   [7372800, 7766016)  wd u32 mfma A-frags [i*512+t]        (live: prep..gru)
//   [0, 655360)         u f16 [b*160+x][256]   (aliases dead gi, post-gru)
//   [655360, 3112960)   w f32 [b*300+t][256]   (aliases dead gi, post-gru)
// ---------------------------------------------------------------------------
extern "C" void kernel_launch(void* const* d_in, const int* in_sizes, int n_in,
                              void* d_out, int out_size, void* d_ws, size_t ws_size,
                              hipStream_t stream) {
    const float* inputs = (const float*)d_in[0];
    const float* memory = (const float*)d_in[1];
    const float* h0 = (const float*)d_in[2];
    const float* Wih = (const float*)d_in[3];
    const float* Whh = (const float*)d_in[4];
    const float* bih = (const float*)d_in[5];
    const float* bhh = (const float*)d_in[6];
    const float* Wm = (const float*)d_in[7];
    const float* Um = (const float*)d_in[8];
    const float* vv = (const float*)d_in[9];

    float* out = (float*)d_out;
    float* out_attn = out;              // 384000
    float* out_outputs = out + 384000;  // 614400
    float* out_hidden = out + 998400;   // 2048

    char* ws = (char*)d_ws;
    float* gi = (float*)ws;
    unsigned* wd = (unsigned*)(ws + 7372800);
    _Float16* u16 = (_Float16*)ws;
    float* wbuf = (float*)(ws + 655360);

    // Phase 1: weight repack + gi GEMM (bias-folded, scattered)
    prep_wd<<<384, 256, 0, stream>>>(Whh, wd);
    gemm_kernel<<<dim3(12, 38), 256, 0, stream>>>(inputs, Wih, gi, nullptr,
                                                  bih, bhh, 2400, 768, 128, 1);
    // Phase 2: sequential GRU (critical path, 8 CUs, weight-stationary MFMA)
    gru_kernel<<<8, 512, 0, stream>>>(gi, wd, h0, bhh, out_outputs, out_hidden);
    // Phase 3: attention precompute + scores/softmax
    gemm_kernel<<<dim3(4, 20), 256, 0, stream>>>(memory, Um, nullptr, u16,
                                                 nullptr, nullptr, 1280, 256, 256, 2);
    gemm_kernel<<<dim3(4, 38), 256, 0, stream>>>(out_outputs, Wm, wbuf, nullptr,
                                                 nullptr, nullptr, 2400, 256, 256, 0);
    attn_kernel<<<dim3(30, 8), 256, 0, stream>>>(u16, wbuf, vv, out_attn);
}

// Round 6
// 496.113 us; speedup vs baseline: 1.1796x; 1.0705x over previous
//
#include <hip/hip_runtime.h>

// Problem constants
// N=8, T_y=300, T_x=160, E=256, E/2=128, 3E=768
// d_out: [attn 8*300*160 = 384000][outputs 8*300*256 = 614400][hidden 2048]

typedef _Float16 f16x2 __attribute__((ext_vector_type(2)));
typedef _Float16 f16x8 __attribute__((ext_vector_type(8)));
typedef float f32x4 __attribute__((ext_vector_type(4)));

__device__ __forceinline__ float fexp2(float x) { return __builtin_amdgcn_exp2f(x); }
__device__ __forceinline__ float frcp(float x) { return __builtin_amdgcn_rcpf(x); }
// sigmoid(x) = 1/(1+2^(-x*log2 e))
__device__ __forceinline__ float fsig(float x) {
    return frcp(1.0f + fexp2(x * -1.4426950408889634f));
}
// tanh(y) = 1 - 2/(1+2^(y*2*log2 e)); saturates correctly at +-inf args
__device__ __forceinline__ float ftanh(float x) {
    return 1.0f - 2.0f * frcp(1.0f + fexp2(x * 2.8853900817779268f));
}

// select component s (0..3) of a f32x4 with runtime s — pure cndmask tree,
// keeps everything in registers (rule #20: no runtime array indexing).
__device__ __forceinline__ float pick4(f32x4 v, int s) {
    float ab = (s & 1) ? v[1] : v[0];
    float cd = (s & 1) ? v[3] : v[2];
    return (s & 2) ? cd : ab;
}

// ---------------------------------------------------------------------------
// Kernel 1 (fused phase 1): blocks 0..383 repack Whh into MFMA A-fragment
// order (prep); blocks 384..839 run the gi GEMM (mode-1: bias-folded,
// scattered). The two jobs are mutually independent and both feed gru —
// fusing removes one launch + gap from the serial chain.
//
// prep layout (verified r2 pass @ absmax 0.0039): gru thread t (of 512):
// wave w=t>>6, lane l=t&63. Wave w owns M-tiles (gate g, half m2): rows
// 256g + 32w + 16*m2 + (l&15). A-frag for mfma_f32_16x16x32_f16: lane l
// holds A[row=l&15][k=(l>>4)*8+i], i=0..7, packed as 4 dwords. Fragment
// fi=(g*2+m2)*8+ks; dword i=fi*4+j. wd layout [i*512+t] (coalesced load).
// ---------------------------------------------------------------------------
__global__ __launch_bounds__(256) void phase1_kernel(
    const float* __restrict__ Whh, unsigned* __restrict__ wd,
    const float* __restrict__ inputs, const float* __restrict__ Wih,
    float* __restrict__ gi, const float* __restrict__ bih,
    const float* __restrict__ bhh) {
    if (blockIdx.x < 384) {
        int gid = blockIdx.x * 256 + threadIdx.x;   // 0..98303 = 192*512
        int i = gid >> 9, t = gid & 511;
        int fi = i >> 2, j = i & 3;
        int g = fi >> 4, m2 = (fi >> 3) & 1, ks = fi & 7;
        int w = t >> 6, l = t & 63;
        int row = 256 * g + 32 * w + 16 * m2 + (l & 15);
        int k = 32 * ks + 8 * (l >> 4) + 2 * j;
        union { unsigned u; f16x2 h; } cv;
        cv.h[0] = (_Float16)Whh[(size_t)row * 256 + k];
        cv.h[1] = (_Float16)Whh[(size_t)row * 256 + k + 1];
        wd[i * 512 + t] = cv.u;
        return;
    }
    // gi GEMM: C[M=2400, N=768] = inputs[2400,128] @ Wih[768,128]^T,
    // scattered store at (t*8+b)*768+col with bias fold.
    int id = blockIdx.x - 384;                   // 0..455 = 12 x 38
    const int n0 = (id % 12) * 64, m0 = (id / 12) * 64;
    __shared__ float Xs[32][65];
    __shared__ float Ws2[32][65];
    const int tid = threadIdx.x;
    const int tx = tid & 15, ty = tid >> 4;
    const int M = 2400, K = 128;
    float acc[4][4] = {};
    for (int k0 = 0; k0 < K; k0 += 32) {
#pragma unroll
        for (int i = 0; i < 8; ++i) {
            int e = tid + i * 256;
            int kk = e & 31, m = e >> 5;
            int row = m0 + m;
            Xs[kk][m] = (row < M) ? inputs[(size_t)row * K + k0 + kk] : 0.0f;
            Ws2[kk][m] = Wih[(size_t)(n0 + m) * K + k0 + kk];
        }
        __syncthreads();
#pragma unroll
        for (int kk = 0; kk < 32; ++kk) {
            float a[4], b[4];
#pragma unroll
            for (int i = 0; i < 4; ++i) a[i] = Xs[kk][ty * 4 + i];
#pragma unroll
            for (int j = 0; j < 4; ++j) b[j] = Ws2[kk][tx * 4 + j];
#pragma unroll
            for (int i = 0; i < 4; ++i)
#pragma unroll
                for (int j = 0; j < 4; ++j) acc[i][j] += a[i] * b[j];
        }
        __syncthreads();
    }
#pragma unroll
    for (int i = 0; i < 4; ++i) {
        int row = m0 + ty * 4 + i;
        if (row >= M) continue;
        int b = row / 300;
        int t = row - b * 300;
#pragma unroll
        for (int j = 0; j < 4; ++j) {
            int col = n0 + tx * 4 + j;
            float val = acc[i][j] + ((col < 512) ? (bih[col] + bhh[col]) : bih[col]);
            gi[(size_t)(t * 8 + b) * 768 + col] = val;
        }
    }
}

// ---------------------------------------------------------------------------
// Kernel B: generic f32 tiled GEMM  C[M,N] = X[M,K] @ Wt[N,K]^T
// mode 0: C f32 natural [row*N+col];  mode 2: C16 f16 natural
// BM=BN=64, BK=32, 256 threads, 4x4 per thread. (Used for w-gemm and the
// u16 fallback path.)
// ---------------------------------------------------------------------------
__global__ __launch_bounds__(256) void gemm_kernel(
    const float* __restrict__ X, const float* __restrict__ Wt,
    float* __restrict__ C, _Float16* __restrict__ C16,
    int M, int N, int K, int mode) {
    __shared__ float Xs[32][65];
    __shared__ float Ws2[32][65];
    const int n0 = blockIdx.x * 64, m0 = blockIdx.y * 64;
    const int tid = threadIdx.x;
    const int tx = tid & 15, ty = tid >> 4;
    float acc[4][4] = {};
    for (int k0 = 0; k0 < K; k0 += 32) {
#pragma unroll
        for (int i = 0; i < 8; ++i) {
            int e = tid + i * 256;
            int kk = e & 31, m = e >> 5;
            int row = m0 + m;
            Xs[kk][m] = (row < M) ? X[(size_t)row * K + k0 + kk] : 0.0f;
            Ws2[kk][m] = Wt[(size_t)(n0 + m) * K + k0 + kk];
        }
        __syncthreads();
#pragma unroll
        for (int kk = 0; kk < 32; ++kk) {
            float a[4], b[4];
#pragma unroll
            for (int i = 0; i < 4; ++i) a[i] = Xs[kk][ty * 4 + i];
#pragma unroll
            for (int j = 0; j < 4; ++j) b[j] = Ws2[kk][tx * 4 + j];
#pragma unroll
            for (int i = 0; i < 4; ++i)
#pragma unroll
                for (int j = 0; j < 4; ++j) acc[i][j] += a[i] * b[j];
        }
        __syncthreads();
    }
#pragma unroll
    for (int i = 0; i < 4; ++i) {
        int row = m0 + ty * 4 + i;
        if (row >= M) continue;
#pragma unroll
        for (int j = 0; j < 4; ++j) {
            int col = n0 + tx * 4 + j;
            if (mode == 2) C16[(size_t)row * N + col] = (_Float16)acc[i][j];
            else           C[(size_t)row * N + col] = acc[i][j];
        }
    }
}

// ---------------------------------------------------------------------------
// Kernel C (fused): blocks 0..7 = GRU recurrence (one batch each, MATRIX
// pipe); blocks 8..87 = the u16 GEMM (memory @ Um^T -> f16), which is
// INDEPENDENT of the GRU and runs concurrently on otherwise-idle CUs.
// (Only when do_u16 != 0, i.e. the workspace has non-aliasing room for u16;
// otherwise grid is 8 and u16 runs separately after, as in round 5.)
//
// GRU core (identical to the passing round-5 version):
// 8 waves, 2/SIMD. Wave w owns gate-colocated M-tiles {r,z,n} x {2w,2w+1}.
// B-operand: h (f16, LDS) replicated across 16 columns -> D replicated ->
// in-register epilogue, one lgkm-only barrier/step, gi prefetched one step
// ahead. Step is matrix-pipe-throughput-bound: 384 MFMA/CU/step = ~1546 cy
// (MfmaUtil 65% measured r5); remaining ~740 cy is LDS RT + epilogue +
// barrier skew.
// CRITICAL: all loops fully unrolled so wf[] indices are compile-time
// constants (rule #20: runtime-indexed arrays go to scratch).
// ---------------------------------------------------------------------------
__global__ __launch_bounds__(512, 1) void gru_fused(
    const float* __restrict__ gi, const unsigned* __restrict__ wd,
    const float* __restrict__ h0, const float* __restrict__ bhh,
    float* __restrict__ outs, float* __restrict__ hid,
    const float* __restrict__ memory, const float* __restrict__ Um,
    _Float16* __restrict__ u16, int do_u16) {
    if (blockIdx.x >= 8) {
        // ---------------- u16 GEMM path (concurrent, idle CUs) ----------
        if (!do_u16) return;
        int id = blockIdx.x - 8;                 // 0..79 = 4 x 20
        const int n0 = (id & 3) * 64, m0 = (id >> 2) * 64;
        __shared__ float Xs[32][65];
        __shared__ float Ws2[32][65];
        const int tid = threadIdx.x;             // 0..511; work on 0..255
        const int tx = tid & 15, ty = (tid & 255) >> 4;
        float acc[4][4] = {};
        for (int k0 = 0; k0 < 256; k0 += 32) {
            if (tid < 256) {
#pragma unroll
                for (int i = 0; i < 8; ++i) {
                    int e = tid + i * 256;
                    int kk = e & 31, m = e >> 5;
                    Xs[kk][m] = memory[(size_t)(m0 + m) * 256 + k0 + kk];
                    Ws2[kk][m] = Um[(size_t)(n0 + m) * 256 + k0 + kk];
                }
            }
            __syncthreads();
            if (tid < 256) {
#pragma unroll
                for (int kk = 0; kk < 32; ++kk) {
                    float a[4], b[4];
#pragma unroll
                    for (int i = 0; i < 4; ++i) a[i] = Xs[kk][ty * 4 + i];
#pragma unroll
                    for (int j = 0; j < 4; ++j) b[j] = Ws2[kk][tx * 4 + j];
#pragma unroll
                    for (int i = 0; i < 4; ++i)
#pragma unroll
                        for (int j = 0; j < 4; ++j) acc[i][j] += a[i] * b[j];
                }
            }
            __syncthreads();
        }
        if (tid < 256) {
#pragma unroll
            for (int i = 0; i < 4; ++i)
#pragma unroll
                for (int j = 0; j < 4; ++j)
                    u16[(size_t)(m0 + ty * 4 + i) * 256 + n0 + tx * 4 + j] =
                        (_Float16)acc[i][j];
        }
        return;
    }
    // -------------------------- GRU path -------------------------------
    const int b = blockIdx.x;
    const int t = threadIdx.x;
    const int w = t >> 6, l = t & 63;
    const int grp = l >> 4;          // D row group / B k-chunk group
    const int sel = l & 7;           // element select within the wave's rows
    const int hi = (l >> 3) & 1;     // duplicate flag (2 lanes per element)
    const int m2s = sel >> 2, rsel = sel & 3;
    const int e = 32 * w + 16 * m2s + 4 * grp + rsel;

    __shared__ __align__(16) _Float16 hbuf[2][256];

    // One-time weight load into 48 A-fragments (192 regs; coalesced).
    f16x8 wf[48];
#pragma unroll
    for (int fi = 0; fi < 48; ++fi) {
        union { unsigned u[4]; f16x8 v; } cv;
#pragma unroll
        for (int j = 0; j < 4; ++j) cv.u[j] = wd[(fi * 4 + j) * 512 + t];
        wf[fi] = cv.v;
    }

    float h = h0[b * 256 + e];
    float bn = bhh[512 + e];         // bhh_n stays inside r*(.)
    if (!hi) hbuf[0][e] = (_Float16)h;
    const float* gp = gi + b * 768;
    float* op = outs + (size_t)b * 76800 + e;

    // Prime the gi pipeline: step-0 values loaded before the loop.
    float gr = gp[e], gz = gp[e + 256], gn = gp[e + 512];
    __syncthreads();

    for (int st = 0; st < 300; ++st) {
        // Prefetch NEXT step's gi (consumed next iteration — one full step
        // of MFMA work hides the L2/HBM latency).
        int stn = (st < 299) ? st + 1 : st;
        const float* g = gp + (size_t)stn * 6144;
        float grn = g[e], gzn = g[e + 256], gnn = g[e + 512];

        const _Float16* hb = hbuf[st & 1];
        // All 8 B-fragments up front; compiler pipelines the ds_reads.
        f16x8 hv0 = *(const f16x8*)(hb + 0 * 32 + 8 * grp);
        f16x8 hv1 = *(const f16x8*)(hb + 1 * 32 + 8 * grp);
        f16x8 hv2 = *(const f16x8*)(hb + 2 * 32 + 8 * grp);
        f16x8 hv3 = *(const f16x8*)(hb + 3 * 32 + 8 * grp);
        f16x8 hv4 = *(const f16x8*)(hb + 4 * 32 + 8 * grp);
        f16x8 hv5 = *(const f16x8*)(hb + 5 * 32 + 8 * grp);
        f16x8 hv6 = *(const f16x8*)(hb + 6 * 32 + 8 * grp);
        f16x8 hv7 = *(const f16x8*)(hb + 7 * 32 + 8 * grp);

        f32x4 aR0 = {0.f, 0.f, 0.f, 0.f}, aR1 = {0.f, 0.f, 0.f, 0.f};
        f32x4 aZ0 = {0.f, 0.f, 0.f, 0.f}, aZ1 = {0.f, 0.f, 0.f, 0.f};
        f32x4 aN0 = {0.f, 0.f, 0.f, 0.f}, aN1 = {0.f, 0.f, 0.f, 0.f};
#define KSTEP(ks, hv)                                                        \
        aR0 = __builtin_amdgcn_mfma_f32_16x16x32_f16(wf[0 * 8 + ks], hv, aR0, 0, 0, 0); \
        aR1 = __builtin_amdgcn_mfma_f32_16x16x32_f16(wf[1 * 8 + ks], hv, aR1, 0, 0, 0); \
        aZ0 = __builtin_amdgcn_mfma_f32_16x16x32_f16(wf[2 * 8 + ks], hv, aZ0, 0, 0, 0); \
        aZ1 = __builtin_amdgcn_mfma_f32_16x16x32_f16(wf[3 * 8 + ks], hv, aZ1, 0, 0, 0); \
        aN0 = __builtin_amdgcn_mfma_f32_16x16x32_f16(wf[4 * 8 + ks], hv, aN0, 0, 0, 0); \
        aN1 = __builtin_amdgcn_mfma_f32_16x16x32_f16(wf[5 * 8 + ks], hv, aN1, 0, 0, 0);
        KSTEP(0, hv0) KSTEP(1, hv1) KSTEP(2, hv2) KSTEP(3, hv3)
        KSTEP(4, hv4) KSTEP(5, hv5) KSTEP(6, hv6) KSTEP(7, hv7)
#undef KSTEP

        // Select this lane's element sums from the replicated fragments.
        f32x4 vR = m2s ? aR1 : aR0;
        f32x4 vZ = m2s ? aZ1 : aZ0;
        f32x4 vN = m2s ? aN1 : aN0;
        float sr = pick4(vR, rsel);
        float sz = pick4(vZ, rsel);
        float sn = pick4(vN, rsel);

        // In-register gate epilogue (each element computed by its 2 lanes).
        float r = fsig(gr + sr);
        float z = fsig(gz + sz);
        float n = ftanh(gn + r * (sn + bn));
        h = n + z * (h - n);

        // Rotate the gi pipeline.
        gr = grn; gz = gzn; gn = gnn;

        if (hi)
            op[st * 256] = h;                       // outs store (no drain)
        else
            hbuf[(st + 1) & 1][e] = (_Float16)h;    // next-h broadcast
        // Fused waitcnt+barrier WITH memory clobber: compiler-level fence in
        // both directions; hardware waits only on LDS (no vmcnt drain — the
        // outs stores and gi prefetch loads stay in flight).
        asm volatile("s_waitcnt lgkmcnt(0)\n\ts_barrier" ::: "memory");
    }
    if (!hi) hid[b * 256 + e] = h;
}

// ---------------------------------------------------------------------------
// Kernel D: scores + softmax. Block = (t-chunk of 10, batch). Threads 0..159
// each own one x. u16 for the whole batch (160x256 f16 = 80KB) is staged in
// LDS once per block with COALESCED global loads. LDS row stride = 129 words
// so the per-x reads are conflict-free.
// ---------------------------------------------------------------------------
__global__ __launch_bounds__(256) void attn_kernel(
    const _Float16* __restrict__ u16, const float* __restrict__ wv,
    const float* __restrict__ v, float* __restrict__ attn) {
    const int tc = blockIdx.x, b = blockIdx.y;
    const int tid = threadIdx.x;
    __shared__ float wL[256], vL[256], sc[160], red[2];
    __shared__ unsigned uS[160 * 129];   // 82560B; f16-pairs, padded rows

    const unsigned* ug = (const unsigned*)(u16 + (size_t)b * 160 * 256);
    for (int i = tid; i < 20480; i += 256) {
        int row = i >> 7, wi = i & 127;
        uS[row * 129 + wi] = ug[i];
    }
    vL[tid] = v[tid];

    for (int ti = 0; ti < 10; ++ti) {
        int t = tc * 10 + ti;
        wL[tid] = wv[(size_t)(b * 300 + t) * 256 + tid];
        __syncthreads();   // first iteration: also covers uS/vL staging
        float acc = 0.0f;
        if (tid < 160) {
            const unsigned* ur = uS + tid * 129;
#pragma unroll 8
            for (int e2 = 0; e2 < 128; ++e2) {
                union { unsigned uu; _Float16 hh[2]; } cv;
                cv.uu = ur[e2];
                int ee = e2 * 2;
                acc += vL[ee] * ftanh(wL[ee] + (float)cv.hh[0]);
                acc += vL[ee + 1] * ftanh(wL[ee + 1] + (float)cv.hh[1]);
            }
            sc[tid] = acc;
        }
        __syncthreads();
        if (tid < 64) {
            float m = -3.0e38f;
            for (int i = tid; i < 160; i += 64) m = fmaxf(m, sc[i]);
#pragma unroll
            for (int o = 32; o; o >>= 1) m = fmaxf(m, __shfl_xor(m, o));
            if (tid == 0) red[0] = m;
        }
        __syncthreads();
        float ee = 0.0f;
        if (tid < 160) {
            ee = fexp2((acc - red[0]) * 1.4426950408889634f);
            sc[tid] = ee;
        }
        __syncthreads();
        if (tid < 64) {
            float s = 0.0f;
            for (int i = tid; i < 160; i += 64) s += sc[i];
#pragma unroll
            for (int o = 32; o; o >>= 1) s += __shfl_xor(s, o);
            if (tid == 0) red[1] = s;
        }
        __syncthreads();
        if (tid < 160)
            attn[(size_t)(b * 300 + t) * 160 + tid] = ee * frcp(red[1]);
        __syncthreads();
    }
}

// ---------------------------------------------------------------------------
// ws layout (bytes):
//   [0, 7372800)        gi f32 [(t*8+b)*768 + col]           (live: K1..gru)
//   [7372800, 7766016)  wd u32 mfma A-frags [i*512+t]        (live: K1..gru)
//   [7766016, 8421376)  u16 f16 [b*160+x][256]  (fused path; needs ws_size)
//   [0, 655360)         u16 fallback           (aliases dead gi, post-gru)
//   [655360, 3112960)   w f32 [b*300+t][256]   (aliases dead gi, post-gru)
// ---------------------------------------------------------------------------
extern "C" void kernel_launch(void* const* d_in, const int* in_sizes, int n_in,
                              void* d_out, int out_size, void* d_ws, size_t ws_size,
                              hipStream_t stream) {
    const float* inputs = (const float*)d_in[0];
    const float* memory = (const float*)d_in[1];
    const float* h0 = (const float*)d_in[2];
    const float* Wih = (const float*)d_in[3];
    const float* Whh = (const float*)d_in[4];
    const float* bih = (const float*)d_in[5];
    const float* bhh = (const float*)d_in[6];
    const float* Wm = (const float*)d_in[7];
    const float* Um = (const float*)d_in[8];
    const float* vv = (const float*)d_in[9];

    float* out = (float*)d_out;
    float* out_attn = out;              // 384000
    float* out_outputs = out + 384000;  // 614400
    float* out_hidden = out + 998400;   // 2048

    char* ws = (char*)d_ws;
    float* gi = (float*)ws;
    unsigned* wd = (unsigned*)(ws + 7372800);
    float* wbuf = (float*)(ws + 655360);

    const size_t U16_OFF = 7766016;
    const bool fuse_u16 = ws_size >= U16_OFF + 655360;
    _Float16* u16 = fuse_u16 ? (_Float16*)(ws + U16_OFF) : (_Float16*)ws;

    // Phase 1: weight repack + gi GEMM in ONE launch (independent jobs).
    phase1_kernel<<<840, 256, 0, stream>>>(Whh, wd, inputs, Wih, gi, bih, bhh);
    // Phase 2: GRU (8 blocks) + concurrent u16 GEMM (80 blocks, idle CUs).
    gru_fused<<<fuse_u16 ? 88 : 8, 512, 0, stream>>>(
        gi, wd, h0, bhh, out_outputs, out_hidden, memory, Um, u16,
        fuse_u16 ? 1 : 0);
    if (!fuse_u16)
        gemm_kernel<<<dim3(4, 20), 256, 0, stream>>>(memory, Um, nullptr, u16,
                                                     1280, 256, 256, 2);
    // Phase 3: w GEMM + scores/softmax (true dependency chain on outputs).
    gemm_kernel<<<dim3(4, 38), 256, 0, stream>>>(out_outputs, Wm, wbuf, nullptr,
                                                 2400, 256, 256, 0);
    attn_kernel<<<dim3(30, 8), 256, 0, stream>>>(u16, wbuf, vv, out_attn);
}

// Round 7
// 489.484 us; speedup vs baseline: 1.1956x; 1.0135x over previous
//
#include <hip/hip_runtime.h>

// Problem constants
// N=8, T_y=300, T_x=160, E=256, E/2=128, 3E=768
// d_out: [attn 8*300*160 = 384000][outputs 8*300*256 = 614400][hidden 2048]

typedef _Float16 f16x2 __attribute__((ext_vector_type(2)));
typedef _Float16 f16x8 __attribute__((ext_vector_type(8)));
typedef float f32x4 __attribute__((ext_vector_type(4)));

__device__ __forceinline__ float fexp2(float x) { return __builtin_amdgcn_exp2f(x); }
__device__ __forceinline__ float frcp(float x) { return __builtin_amdgcn_rcpf(x); }
__device__ __forceinline__ float fsig(float x) {
    return frcp(1.0f + fexp2(x * -1.4426950408889634f));
}
__device__ __forceinline__ float ftanh(float x) {
    return 1.0f - 2.0f * frcp(1.0f + fexp2(x * 2.8853900817779268f));
}

// select component s (0..3) of a f32x4 with runtime s — pure cndmask tree
// (rule #20: no runtime array indexing).
__device__ __forceinline__ float pick4(f32x4 v, int s) {
    float ab = (s & 1) ? v[1] : v[0];
    float cd = (s & 1) ? v[3] : v[2];
    return (s & 2) ? cd : ab;
}

// ---------------------------------------------------------------------------
// Kernel 1 (phase 1): blocks 0..383 repack Whh into MFMA A-fragment order;
// blocks 384..839 run the gi GEMM (bias-folded, scattered). Block 0 also
// zeroes the producer/consumer flags (visible to the mega kernel via the
// launch boundary). Layout verified r2+ (absmax 0.0039).
// ---------------------------------------------------------------------------
__global__ __launch_bounds__(256) void phase1_kernel(
    const float* __restrict__ Whh, unsigned* __restrict__ wd,
    const float* __restrict__ inputs, const float* __restrict__ Wih,
    float* __restrict__ gi, const float* __restrict__ bih,
    const float* __restrict__ bhh, int* flags, int full) {
    if (full && blockIdx.x == 0 && threadIdx.x < 10) flags[threadIdx.x] = 0;
    if (blockIdx.x < 384) {
        int gid = blockIdx.x * 256 + threadIdx.x;   // 0..98303 = 192*512
        int i = gid >> 9, t = gid & 511;
        int fi = i >> 2, j = i & 3;
        int g = fi >> 4, m2 = (fi >> 3) & 1, ks = fi & 7;
        int w = t >> 6, l = t & 63;
        int row = 256 * g + 32 * w + 16 * m2 + (l & 15);
        int k = 32 * ks + 8 * (l >> 4) + 2 * j;
        union { unsigned u; f16x2 h; } cv;
        cv.h[0] = (_Float16)Whh[(size_t)row * 256 + k];
        cv.h[1] = (_Float16)Whh[(size_t)row * 256 + k + 1];
        wd[i * 512 + t] = cv.u;
        return;
    }
    int id = blockIdx.x - 384;                   // 0..455 = 12 x 38
    const int n0 = (id % 12) * 64, m0 = (id / 12) * 64;
    __shared__ float Xs[32][65];
    __shared__ float Ws2[32][65];
    const int tid = threadIdx.x;
    const int tx = tid & 15, ty = tid >> 4;
    const int M = 2400, K = 128;
    float acc[4][4] = {};
    for (int k0 = 0; k0 < K; k0 += 32) {
#pragma unroll
        for (int i = 0; i < 8; ++i) {
            int e = tid + i * 256;
            int kk = e & 31, m = e >> 5;
            int row = m0 + m;
            Xs[kk][m] = (row < M) ? inputs[(size_t)row * K + k0 + kk] : 0.0f;
            Ws2[kk][m] = Wih[(size_t)(n0 + m) * K + k0 + kk];
        }
        __syncthreads();
#pragma unroll
        for (int kk = 0; kk < 32; ++kk) {
            float a[4], b[4];
#pragma unroll
            for (int i = 0; i < 4; ++i) a[i] = Xs[kk][ty * 4 + i];
#pragma unroll
            for (int j = 0; j < 4; ++j) b[j] = Ws2[kk][tx * 4 + j];
#pragma unroll
            for (int i = 0; i < 4; ++i)
#pragma unroll
                for (int j = 0; j < 4; ++j) acc[i][j] += a[i] * b[j];
        }
        __syncthreads();
    }
#pragma unroll
    for (int i = 0; i < 4; ++i) {
        int row = m0 + ty * 4 + i;
        if (row >= M) continue;
        int b = row / 300;
        int t = row - b * 300;
#pragma unroll
        for (int j = 0; j < 4; ++j) {
            int col = n0 + tx * 4 + j;
            float val = acc[i][j] + ((col < 512) ? (bih[col] + bhh[col]) : bih[col]);
            gi[(size_t)(t * 8 + b) * 768 + col] = val;
        }
    }
}

// ---------------------------------------------------------------------------
// Kernel B (FALLBACK only): generic f32 tiled GEMM  C = X @ Wt^T.
// mode 0: C f32; mode 2: C16 f16.
// ---------------------------------------------------------------------------
__global__ __launch_bounds__(256) void gemm_kernel(
    const float* __restrict__ X, const float* __restrict__ Wt,
    float* __restrict__ C, _Float16* __restrict__ C16,
    int M, int N, int K, int mode) {
    __shared__ float Xs[32][65];
    __shared__ float Ws2[32][65];
    const int n0 = blockIdx.x * 64, m0 = blockIdx.y * 64;
    const int tid = threadIdx.x;
    const int tx = tid & 15, ty = tid >> 4;
    float acc[4][4] = {};
    for (int k0 = 0; k0 < K; k0 += 32) {
#pragma unroll
        for (int i = 0; i < 8; ++i) {
            int e = tid + i * 256;
            int kk = e & 31, m = e >> 5;
            int row = m0 + m;
            Xs[kk][m] = (row < M) ? X[(size_t)row * K + k0 + kk] : 0.0f;
            Ws2[kk][m] = Wt[(size_t)(n0 + m) * K + k0 + kk];
        }
        __syncthreads();
#pragma unroll
        for (int kk = 0; kk < 32; ++kk) {
            float a[4], b[4];
#pragma unroll
            for (int i = 0; i < 4; ++i) a[i] = Xs[kk][ty * 4 + i];
#pragma unroll
            for (int j = 0; j < 4; ++j) b[j] = Ws2[kk][tx * 4 + j];
#pragma unroll
            for (int i = 0; i < 4; ++i)
#pragma unroll
                for (int j = 0; j < 4; ++j) acc[i][j] += a[i] * b[j];
        }
        __syncthreads();
    }
#pragma unroll
    for (int i = 0; i < 4; ++i) {
        int row = m0 + ty * 4 + i;
        if (row >= M) continue;
#pragma unroll
        for (int j = 0; j < 4; ++j) {
            int col = n0 + tx * 4 + j;
            if (mode == 2) C16[(size_t)row * N + col] = (_Float16)acc[i][j];
            else           C[(size_t)row * N + col] = acc[i][j];
        }
    }
}

// ---------------------------------------------------------------------------
// Kernel C (mega): 88 blocks x 512 threads, all co-resident (<=256 CUs, so
// the spin protocol is deadlock-free by construction).
//   blocks 0..7  : GRU recurrence (identical hot loop to the passing r5/r6
//                  version) + progress publish every 32 steps:
//                  per-wave vmcnt(0) -> __syncthreads -> tid0 RELEASE-store
//                  of step count (agent scope: flushes XCD L2 so consumers
//                  see the outs rows).
//   blocks 8..87 : u16 GEMM tile (as r6), then RELEASE-increment flags[8];
//                  then become attention consumers: group g=id/10 owns
//                  batch g; block j=id%10 processes t-chunks {j, j+10, j+20}.
//                  Per chunk: ACQUIRE-spin on prog[batch] (invalidates
//                  L1+L2 -> no stale memset-0 lines), stage 10 outputs rows,
//                  compute w = rows @ W^T in-block (f32, numerics identical
//                  to the old w-GEMM), then scores+softmax (r6 attn code).
// Everything except the ~8us final chunk hides under the gru's 286us.
// CRITICAL (gru): all loops fully unrolled so wf[] indices are compile-time
// constants (rule #20).
// ---------------------------------------------------------------------------
__global__ __launch_bounds__(512, 1) void gru_mega(
    const float* __restrict__ gi, const unsigned* __restrict__ wd,
    const float* __restrict__ h0, const float* __restrict__ bhh,
    float* __restrict__ outs, float* __restrict__ hid,
    const float* __restrict__ memory, const float* __restrict__ Um,
    _Float16* __restrict__ u16, const float* __restrict__ W,
    const float* __restrict__ vv, float* __restrict__ attn,
    int* flags, int full) {
    __shared__ __align__(16) _Float16 hbuf[2][256];
    __shared__ float Xs[32][65];
    __shared__ float Ws2[32][65];
    __shared__ unsigned uS[160 * 129];            // 82560B
    __shared__ __align__(16) float oL[10][260];   // outputs rows (padded)
    __shared__ float wLf[10][256];
    __shared__ float vL[256], sc[160], red[2];

    const int tid = threadIdx.x;

    if (blockIdx.x >= 8) {
        // ---------------- u16 GEMM tile (concurrent with gru) ------------
        int id = blockIdx.x - 8;                 // 0..79 = 4 x 20
        const int n0 = (id & 3) * 64, m0 = (id >> 2) * 64;
        const int tx = tid & 15, ty = (tid & 255) >> 4;
        float acc[4][4] = {};
        for (int k0 = 0; k0 < 256; k0 += 32) {
            if (tid < 256) {
#pragma unroll
                for (int i = 0; i < 8; ++i) {
                    int e = tid + i * 256;
                    int kk = e & 31, m = e >> 5;
                    Xs[kk][m] = memory[(size_t)(m0 + m) * 256 + k0 + kk];
                    Ws2[kk][m] = Um[(size_t)(n0 + m) * 256 + k0 + kk];
                }
            }
            __syncthreads();
            if (tid < 256) {
#pragma unroll
                for (int kk = 0; kk < 32; ++kk) {
                    float a[4], b[4];
#pragma unroll
                    for (int i = 0; i < 4; ++i) a[i] = Xs[kk][ty * 4 + i];
#pragma unroll
                    for (int j = 0; j < 4; ++j) b[j] = Ws2[kk][tx * 4 + j];
#pragma unroll
                    for (int i = 0; i < 4; ++i)
#pragma unroll
                        for (int j = 0; j < 4; ++j) acc[i][j] += a[i] * b[j];
                }
            }
            __syncthreads();
        }
        if (tid < 256) {
#pragma unroll
            for (int i = 0; i < 4; ++i)
#pragma unroll
                for (int j = 0; j < 4; ++j)
                    u16[(size_t)(m0 + ty * 4 + i) * 256 + n0 + tx * 4 + j] =
                        (_Float16)acc[i][j];
        }
        if (!full) return;                       // fallback: u16 only
        __syncthreads();
        if (tid == 0)
            __hip_atomic_fetch_add(&flags[8], 1, __ATOMIC_RELEASE,
                                   __HIP_MEMORY_SCOPE_AGENT);

        // ---------------- attention consumer ----------------------------
        const int grp = id / 10;                 // batch
        const int jj = id % 10;
        // wait all 80 u16 tiles (ACQUIRE -> L1+L2 invalidate)
        if (tid == 0) {
            while (__hip_atomic_load(&flags[8], __ATOMIC_ACQUIRE,
                                     __HIP_MEMORY_SCOPE_AGENT) < 80)
                __builtin_amdgcn_s_sleep(64);
        }
        __syncthreads();
        // stage uS for this batch once (coalesced; padded rows -> no bank
        // conflicts on the per-x reads)
        const unsigned* ug = (const unsigned*)(u16 + (size_t)grp * 160 * 256);
        for (int i = tid; i < 20480; i += 512)
            uS[(i >> 7) * 129 + (i & 127)] = ug[i];
        if (tid < 256) vL[tid] = vv[tid];
        __syncthreads();

        for (int uu = 0; uu < 3; ++uu) {
            const int tc = jj + uu * 10;
            const int need = tc * 10 + 10;
            if (tid == 0) {
                while (__hip_atomic_load(&flags[grp], __ATOMIC_ACQUIRE,
                                         __HIP_MEMORY_SCOPE_AGENT) < need)
                    __builtin_amdgcn_s_sleep(64);
            }
            __syncthreads();
            // stage the 10 outputs rows
            for (int i = tid; i < 2560; i += 512) {
                int ti = i >> 8, k = i & 255;
                oL[ti][k] = outs[((size_t)grp * 300 + tc * 10 + ti) * 256 + k];
            }
            __syncthreads();
            // w = rows @ W^T  (thread c owns column c; f32, exact old math)
            if (tid < 256) {
                float a0 = 0, a1 = 0, a2 = 0, a3 = 0, a4 = 0;
                float a5 = 0, a6 = 0, a7 = 0, a8 = 0, a9 = 0;
                for (int k4 = 0; k4 < 256; k4 += 4) {
                    float4 wq = *(const float4*)(W + (size_t)tid * 256 + k4);
#define WROW(ACC, TI)                                                     \
                    {                                                     \
                        float4 oq = *(const float4*)(&oL[TI][k4]);        \
                        ACC += wq.x * oq.x + wq.y * oq.y +                \
                               wq.z * oq.z + wq.w * oq.w;                 \
                    }
                    WROW(a0, 0) WROW(a1, 1) WROW(a2, 2) WROW(a3, 3) WROW(a4, 4)
                    WROW(a5, 5) WROW(a6, 6) WROW(a7, 7) WROW(a8, 8) WROW(a9, 9)
#undef WROW
                }
                wLf[0][tid] = a0; wLf[1][tid] = a1; wLf[2][tid] = a2;
                wLf[3][tid] = a3; wLf[4][tid] = a4; wLf[5][tid] = a5;
                wLf[6][tid] = a6; wLf[7][tid] = a7; wLf[8][tid] = a8;
                wLf[9][tid] = a9;
            }
            __syncthreads();
            // scores + softmax (r6 attn code, wLf instead of global wv)
            for (int ti = 0; ti < 10; ++ti) {
                int t = tc * 10 + ti;
                float acc2 = 0.0f;
                if (tid < 160) {
                    const unsigned* ur = uS + tid * 129;
                    const float* wl = wLf[ti];
#pragma unroll 8
                    for (int e2 = 0; e2 < 128; ++e2) {
                        union { unsigned uu2; _Float16 hh[2]; } cv;
                        cv.uu2 = ur[e2];
                        int ee = e2 * 2;
                        acc2 += vL[ee] * ftanh(wl[ee] + (float)cv.hh[0]);
                        acc2 += vL[ee + 1] * ftanh(wl[ee + 1] + (float)cv.hh[1]);
                    }
                    sc[tid] = acc2;
                }
                __syncthreads();
                if (tid < 64) {
                    float m = -3.0e38f;
                    for (int i = tid; i < 160; i += 64) m = fmaxf(m, sc[i]);
#pragma unroll
                    for (int o = 32; o; o >>= 1) m = fmaxf(m, __shfl_xor(m, o));
                    if (tid == 0) red[0] = m;
                }
                __syncthreads();
                float ee = 0.0f;
                if (tid < 160) {
                    ee = fexp2((acc2 - red[0]) * 1.4426950408889634f);
                    sc[tid] = ee;
                }
                __syncthreads();
                if (tid < 64) {
                    float s = 0.0f;
                    for (int i = tid; i < 160; i += 64) s += sc[i];
#pragma unroll
                    for (int o = 32; o; o >>= 1) s += __shfl_xor(s, o);
                    if (tid == 0) red[1] = s;
                }
                __syncthreads();
                if (tid < 160)
                    attn[(size_t)(grp * 300 + t) * 160 + tid] = ee * frcp(red[1]);
                __syncthreads();
            }
        }
        return;
    }

    // -------------------------- GRU path -------------------------------
    const int b = blockIdx.x;
    const int t = tid;
    const int w = t >> 6, l = t & 63;
    const int grp = l >> 4;
    const int sel = l & 7;
    const int hi = (l >> 3) & 1;
    const int m2s = sel >> 2, rsel = sel & 3;
    const int e = 32 * w + 16 * m2s + 4 * grp + rsel;

    f16x8 wf[48];
#pragma unroll
    for (int fi = 0; fi < 48; ++fi) {
        union { unsigned u[4]; f16x8 v; } cv;
#pragma unroll
        for (int j = 0; j < 4; ++j) cv.u[j] = wd[(fi * 4 + j) * 512 + t];
        wf[fi] = cv.v;
    }

    float h = h0[b * 256 + e];
    float bn = bhh[512 + e];
    if (!hi) hbuf[0][e] = (_Float16)h;
    const float* gp = gi + b * 768;
    float* op = outs + (size_t)b * 76800 + e;

    float gr = gp[e], gz = gp[e + 256], gn = gp[e + 512];
    __syncthreads();

    for (int st = 0; st < 300; ++st) {
        // Progress publish (uniform branch): drain each wave's stores, then
        // one RELEASE-store of the step count. Placed BEFORE the prefetch
        // issue so vmcnt(0) only waits old outs stores (~0 cost).
        if (full && (st & 31) == 0 && st) {
            asm volatile("s_waitcnt vmcnt(0)" ::: "memory");
            __syncthreads();
            if (t == 0)
                __hip_atomic_store(&flags[b], st, __ATOMIC_RELEASE,
                                   __HIP_MEMORY_SCOPE_AGENT);
        }
        int stn = (st < 299) ? st + 1 : st;
        const float* g = gp + (size_t)stn * 6144;
        float grn = g[e], gzn = g[e + 256], gnn = g[e + 512];

        const _Float16* hb = hbuf[st & 1];
        f16x8 hv0 = *(const f16x8*)(hb + 0 * 32 + 8 * grp);
        f16x8 hv1 = *(const f16x8*)(hb + 1 * 32 + 8 * grp);
        f16x8 hv2 = *(const f16x8*)(hb + 2 * 32 + 8 * grp);
        f16x8 hv3 = *(const f16x8*)(hb + 3 * 32 + 8 * grp);
        f16x8 hv4 = *(const f16x8*)(hb + 4 * 32 + 8 * grp);
        f16x8 hv5 = *(const f16x8*)(hb + 5 * 32 + 8 * grp);
        f16x8 hv6 = *(const f16x8*)(hb + 6 * 32 + 8 * grp);
        f16x8 hv7 = *(const f16x8*)(hb + 7 * 32 + 8 * grp);

        f32x4 aR0 = {0.f, 0.f, 0.f, 0.f}, aR1 = {0.f, 0.f, 0.f, 0.f};
        f32x4 aZ0 = {0.f, 0.f, 0.f, 0.f}, aZ1 = {0.f, 0.f, 0.f, 0.f};
        f32x4 aN0 = {0.f, 0.f, 0.f, 0.f}, aN1 = {0.f, 0.f, 0.f, 0.f};
#define KSTEP(ks, hv)                                                        \
        aR0 = __builtin_amdgcn_mfma_f32_16x16x32_f16(wf[0 * 8 + ks], hv, aR0, 0, 0, 0); \
        aR1 = __builtin_amdgcn_mfma_f32_16x16x32_f16(wf[1 * 8 + ks], hv, aR1, 0, 0, 0); \
        aZ0 = __builtin_amdgcn_mfma_f32_16x16x32_f16(wf[2 * 8 + ks], hv, aZ0, 0, 0, 0); \
        aZ1 = __builtin_amdgcn_mfma_f32_16x16x32_f16(wf[3 * 8 + ks], hv, aZ1, 0, 0, 0); \
        aN0 = __builtin_amdgcn_mfma_f32_16x16x32_f16(wf[4 * 8 + ks], hv, aN0, 0, 0, 0); \
        aN1 = __builtin_amdgcn_mfma_f32_16x16x32_f16(wf[5 * 8 + ks], hv, aN1, 0, 0, 0);
        KSTEP(0, hv0) KSTEP(1, hv1) KSTEP(2, hv2) KSTEP(3, hv3)
        KSTEP(4, hv4) KSTEP(5, hv5) KSTEP(6, hv6) KSTEP(7, hv7)
#undef KSTEP

        f32x4 vR = m2s ? aR1 : aR0;
        f32x4 vZ = m2s ? aZ1 : aZ0;
        f32x4 vN = m2s ? aN1 : aN0;
        float sr = pick4(vR, rsel);
        float sz = pick4(vZ, rsel);
        float sn = pick4(vN, rsel);

        float r = fsig(gr + sr);
        float z = fsig(gz + sz);
        float n = ftanh(gn + r * (sn + bn));
        h = n + z * (h - n);

        gr = grn; gz = gzn; gn = gnn;

        if (hi)
            op[st * 256] = h;
        else
            hbuf[(st + 1) & 1][e] = (_Float16)h;
        asm volatile("s_waitcnt lgkmcnt(0)\n\ts_barrier" ::: "memory");
    }
    if (full) {
        asm volatile("s_waitcnt vmcnt(0)" ::: "memory");
        __syncthreads();
        if (t == 0)
            __hip_atomic_store(&flags[b], 300, __ATOMIC_RELEASE,
                               __HIP_MEMORY_SCOPE_AGENT);
    }
    if (!hi) hid[b * 256 + e] = h;
}

// ---------------------------------------------------------------------------
// Kernel D (FALLBACK only): r6 attn kernel (reads precomputed wv).
// ---------------------------------------------------------------------------
__global__ __launch_bounds__(256) void attn_kernel(
    const _Float16* __restrict__ u16, const float* __restrict__ wv,
    const float* __restrict__ v, float* __restrict__ attn) {
    const int tc = blockIdx.x, b = blockIdx.y;
    const int tid = threadIdx.x;
    __shared__ float wL[256], vL[256], sc[160], red[2];
    __shared__ unsigned uS[160 * 129];

    const unsigned* ug = (const unsigned*)(u16 + (size_t)b * 160 * 256);
    for (int i = tid; i < 20480; i += 256)
        uS[(i >> 7) * 129 + (i & 127)] = ug[i];
    vL[tid] = v[tid];

    for (int ti = 0; ti < 10; ++ti) {
        int t = tc * 10 + ti;
        wL[tid] = wv[(size_t)(b * 300 + t) * 256 + tid];
        __syncthreads();
        float acc = 0.0f;
        if (tid < 160) {
            const unsigned* ur = uS + tid * 129;
#pragma unroll 8
            for (int e2 = 0; e2 < 128; ++e2) {
                union { unsigned uu; _Float16 hh[2]; } cv;
                cv.uu = ur[e2];
                int ee = e2 * 2;
                acc += vL[ee] * ftanh(wL[ee] + (float)cv.hh[0]);
                acc += vL[ee + 1] * ftanh(wL[ee + 1] + (float)cv.hh[1]);
            }
            sc[tid] = acc;
        }
        __syncthreads();
        if (tid < 64) {
            float m = -3.0e38f;
            for (int i = tid; i < 160; i += 64) m = fmaxf(m, sc[i]);
#pragma unroll
            for (int o = 32; o; o >>= 1) m = fmaxf(m, __shfl_xor(m, o));
            if (tid == 0) red[0] = m;
        }
        __syncthreads();
        float ee = 0.0f;
        if (tid < 160) {
            ee = fexp2((acc - red[0]) * 1.4426950408889634f);
            sc[tid] = ee;
        }
        __syncthreads();
        if (tid < 64) {
            float s = 0.0f;
            for (int i = tid; i < 160; i += 64) s += sc[i];
#pragma unroll
            for (int o = 32; o; o >>= 1) s += __shfl_xor(s, o);
            if (tid == 0) red[1] = s;
        }
        __syncthreads();
        if (tid < 160)
            attn[(size_t)(b * 300 + t) * 160 + tid] = ee * frcp(red[1]);
        __syncthreads();
    }
}

// ---------------------------------------------------------------------------
// ws layout (bytes):
//   [0, 7372800)        gi f32 [(t*8+b)*768 + col]
//   [7372800, 7766016)  wd u32 mfma A-frags [i*512+t]
//   [7766016, 8421376)  u16 f16 [b*160+x][256]   (full path)
//   [8421376, 8421416)  flags: prog[8], u16done  (full path)
//   fallback: u16 at ws+0, wbuf at ws+655360 (post-gru aliasing, as r5)
// ---------------------------------------------------------------------------
extern "C" void kernel_launch(void* const* d_in, const int* in_sizes, int n_in,
                              void* d_out, int out_size, void* d_ws, size_t ws_size,
                              hipStream_t stream) {
    const float* inputs = (const float*)d_in[0];
    const float* memory = (const float*)d_in[1];
    const float* h0 = (const float*)d_in[2];
    const float* Wih = (const float*)d_in[3];
    const float* Whh = (const float*)d_in[4];
    const float* bih = (const float*)d_in[5];
    const float* bhh = (const float*)d_in[6];
    const float* Wm = (const float*)d_in[7];
    const float* Um = (const float*)d_in[8];
    const float* vv = (const float*)d_in[9];

    float* out = (float*)d_out;
    float* out_attn = out;              // 384000
    float* out_outputs = out + 384000;  // 614400
    float* out_hidden = out + 998400;   // 2048

    char* ws = (char*)d_ws;
    float* gi = (float*)ws;
    unsigned* wd = (unsigned*)(ws + 7372800);

    const size_t U16_OFF = 7766016, FLAG_OFF = 8421376;
    const bool full = ws_size >= FLAG_OFF + 64;
    _Float16* u16 = full ? (_Float16*)(ws + U16_OFF) : (_Float16*)ws;
    int* flags = (int*)(ws + FLAG_OFF);

    // Phase 1: weight repack + gi GEMM + flag zeroing (one launch).
    phase1_kernel<<<840, 256, 0, stream>>>(Whh, wd, inputs, Wih, gi, bih, bhh,
                                           flags, full ? 1 : 0);
    if (full) {
        // Phase 2: GRU + u16 GEMM + overlapped w/attention consumers.
        gru_mega<<<88, 512, 0, stream>>>(gi, wd, h0, bhh, out_outputs,
                                         out_hidden, memory, Um, u16, Wm, vv,
                                         out_attn, flags, 1);
    } else {
        // Fallback: r5-style serial pipeline.
        float* wbuf = (float*)(ws + 655360);
        gru_mega<<<8, 512, 0, stream>>>(gi, wd, h0, bhh, out_outputs,
                                        out_hidden, memory, Um, u16, Wm, vv,
                                        out_attn, flags, 0);
        gemm_kernel<<<dim3(4, 20), 256, 0, stream>>>(memory, Um, nullptr, u16,
                                                     1280, 256, 256, 2);
        gemm_kernel<<<dim3(4, 38), 256, 0, stream>>>(out_outputs, Wm, wbuf,
                                                     nullptr, 2400, 256, 256, 0);
        attn_kernel<<<dim3(30, 8), 256, 0, stream>>>(u16, wbuf, vv, out_attn);
    }
}

// Round 8
// 467.604 us; speedup vs baseline: 1.2515x; 1.0468x over previous
//
#include <hip/hip_runtime.h>

// Problem constants
// N=8, T_y=300, T_x=160, E=256, E/2=128, 3E=768
// d_out: [attn 8*300*160 = 384000][outputs 8*300*256 = 614400][hidden 2048]

typedef _Float16 f16x2 __attribute__((ext_vector_type(2)));
typedef _Float16 f16x8 __attribute__((ext_vector_type(8)));
typedef float f32x4 __attribute__((ext_vector_type(4)));

__device__ __forceinline__ float fexp2(float x) { return __builtin_amdgcn_exp2f(x); }
__device__ __forceinline__ float frcp(float x) { return __builtin_amdgcn_rcpf(x); }
__device__ __forceinline__ float fsig(float x) {
    return frcp(1.0f + fexp2(x * -1.4426950408889634f));
}
__device__ __forceinline__ float ftanh(float x) {
    return 1.0f - 2.0f * frcp(1.0f + fexp2(x * 2.8853900817779268f));
}

// select component s (0..3) of a f32x4 with runtime s — pure cndmask tree
// (rule #20: no runtime array indexing).
__device__ __forceinline__ float pick4(f32x4 v, int s) {
    float ab = (s & 1) ? v[1] : v[0];
    float cd = (s & 1) ? v[3] : v[2];
    return (s & 2) ? cd : ab;
}

// ---------------------------------------------------------------------------
// Kernel 1 (phase 1): blocks 0..383 repack Whh into MFMA A-fragment order;
// blocks 384..839 run the gi GEMM (bias-folded, scattered). Block 0 also
// zeroes the producer/consumer flags (visible to the mega kernel via the
// launch boundary). Layout verified r2+ (absmax 0.0039).
// ---------------------------------------------------------------------------
__global__ __launch_bounds__(256) void phase1_kernel(
    const float* __restrict__ Whh, unsigned* __restrict__ wd,
    const float* __restrict__ inputs, const float* __restrict__ Wih,
    float* __restrict__ gi, const float* __restrict__ bih,
    const float* __restrict__ bhh, int* flags, int full) {
    if (full && blockIdx.x == 0 && threadIdx.x < 10) flags[threadIdx.x] = 0;
    if (blockIdx.x < 384) {
        int gid = blockIdx.x * 256 + threadIdx.x;   // 0..98303 = 192*512
        int i = gid >> 9, t = gid & 511;
        int fi = i >> 2, j = i & 3;
        int g = fi >> 4, m2 = (fi >> 3) & 1, ks = fi & 7;
        int w = t >> 6, l = t & 63;
        int row = 256 * g + 32 * w + 16 * m2 + (l & 15);
        int k = 32 * ks + 8 * (l >> 4) + 2 * j;
        union { unsigned u; f16x2 h; } cv;
        cv.h[0] = (_Float16)Whh[(size_t)row * 256 + k];
        cv.h[1] = (_Float16)Whh[(size_t)row * 256 + k + 1];
        wd[i * 512 + t] = cv.u;
        return;
    }
    int id = blockIdx.x - 384;                   // 0..455 = 12 x 38
    const int n0 = (id % 12) * 64, m0 = (id / 12) * 64;
    __shared__ float Xs[32][65];
    __shared__ float Ws2[32][65];
    const int tid = threadIdx.x;
    const int tx = tid & 15, ty = tid >> 4;
    const int M = 2400, K = 128;
    float acc[4][4] = {};
    for (int k0 = 0; k0 < K; k0 += 32) {
#pragma unroll
        for (int i = 0; i < 8; ++i) {
            int e = tid + i * 256;
            int kk = e & 31, m = e >> 5;
            int row = m0 + m;
            Xs[kk][m] = (row < M) ? inputs[(size_t)row * K + k0 + kk] : 0.0f;
            Ws2[kk][m] = Wih[(size_t)(n0 + m) * K + k0 + kk];
        }
        __syncthreads();
#pragma unroll
        for (int kk = 0; kk < 32; ++kk) {
            float a[4], b[4];
#pragma unroll
            for (int i = 0; i < 4; ++i) a[i] = Xs[kk][ty * 4 + i];
#pragma unroll
            for (int j = 0; j < 4; ++j) b[j] = Ws2[kk][tx * 4 + j];
#pragma unroll
            for (int i = 0; i < 4; ++i)
#pragma unroll
                for (int j = 0; j < 4; ++j) acc[i][j] += a[i] * b[j];
        }
        __syncthreads();
    }
#pragma unroll
    for (int i = 0; i < 4; ++i) {
        int row = m0 + ty * 4 + i;
        if (row >= M) continue;
        int b = row / 300;
        int t = row - b * 300;
#pragma unroll
        for (int j = 0; j < 4; ++j) {
            int col = n0 + tx * 4 + j;
            float val = acc[i][j] + ((col < 512) ? (bih[col] + bhh[col]) : bih[col]);
            gi[(size_t)(t * 8 + b) * 768 + col] = val;
        }
    }
}

// ---------------------------------------------------------------------------
// Kernel B (FALLBACK only): generic f32 tiled GEMM  C = X @ Wt^T.
// mode 0: C f32; mode 2: C16 f16.
// ---------------------------------------------------------------------------
__global__ __launch_bounds__(256) void gemm_kernel(
    const float* __restrict__ X, const float* __restrict__ Wt,
    float* __restrict__ C, _Float16* __restrict__ C16,
    int M, int N, int K, int mode) {
    __shared__ float Xs[32][65];
    __shared__ float Ws2[32][65];
    const int n0 = blockIdx.x * 64, m0 = blockIdx.y * 64;
    const int tid = threadIdx.x;
    const int tx = tid & 15, ty = tid >> 4;
    float acc[4][4] = {};
    for (int k0 = 0; k0 < K; k0 += 32) {
#pragma unroll
        for (int i = 0; i < 8; ++i) {
            int e = tid + i * 256;
            int kk = e & 31, m = e >> 5;
            int row = m0 + m;
            Xs[kk][m] = (row < M) ? X[(size_t)row * K + k0 + kk] : 0.0f;
            Ws2[kk][m] = Wt[(size_t)(n0 + m) * K + k0 + kk];
        }
        __syncthreads();
#pragma unroll
        for (int kk = 0; kk < 32; ++kk) {
            float a[4], b[4];
#pragma unroll
            for (int i = 0; i < 4; ++i) a[i] = Xs[kk][ty * 4 + i];
#pragma unroll
            for (int j = 0; j < 4; ++j) b[j] = Ws2[kk][tx * 4 + j];
#pragma unroll
            for (int i = 0; i < 4; ++i)
#pragma unroll
                for (int j = 0; j < 4; ++j) acc[i][j] += a[i] * b[j];
        }
        __syncthreads();
    }
#pragma unroll
    for (int i = 0; i < 4; ++i) {
        int row = m0 + ty * 4 + i;
        if (row >= M) continue;
#pragma unroll
        for (int j = 0; j < 4; ++j) {
            int col = n0 + tx * 4 + j;
            if (mode == 2) C16[(size_t)row * N + col] = (_Float16)acc[i][j];
            else           C[(size_t)row * N + col] = acc[i][j];
        }
    }
}

// ---------------------------------------------------------------------------
// Kernel C (mega): 248 blocks x 512 threads, all co-resident (248 <= 256 CUs
// at 1 block/CU -> spin protocol deadlock-free by construction).
//   blocks 0..7   : GRU recurrence — EXACT r5/r6 hot loop, ZERO in-loop sync.
//                   ONE publish at the end (vmcnt drain -> syncthreads ->
//                   tid0 RELEASE store). r7's 10 in-loop publishes cost
//                   ~114us (each agent-RELEASE = buffer_wbl2 L2 writeback).
//   blocks 8..247 : id = blk-8 in 0..239. id<80: u16 GEMM tile, then
//                   RELEASE-increment flags[8]. All: RELAXED-poll flags
//                   (read-through, NO buffer_inv per poll — r7's ACQUIRE
//                   polls invalidated XCD L2s under the gru), one ACQUIRE
//                   confirmation when ready. Then ONE (batch=id/30,
//                   tc=id%30) chunk: stage 10 outs rows, w = rows @ W^T
//                   in-block (f32, numerics = old w-GEMM), scores+softmax.
// Tail after gru ends: one chunk (~8us) instead of r7's three.
// CRITICAL (gru): all loops fully unrolled so wf[] indices are compile-time
// constants (rule #20).
// ---------------------------------------------------------------------------
__global__ __launch_bounds__(512, 1) void gru_mega(
    const float* __restrict__ gi, const unsigned* __restrict__ wd,
    const float* __restrict__ h0, const float* __restrict__ bhh,
    float* __restrict__ outs, float* __restrict__ hid,
    const float* __restrict__ memory, const float* __restrict__ Um,
    _Float16* __restrict__ u16, const float* __restrict__ W,
    const float* __restrict__ vv, float* __restrict__ attn,
    int* flags, int full) {
    __shared__ __align__(16) _Float16 hbuf[2][256];
    __shared__ float Xs[32][65];
    __shared__ float Ws2[32][65];
    __shared__ unsigned uS[160 * 129];            // 82560B
    __shared__ __align__(16) float oL[10][260];   // outputs rows (padded)
    __shared__ float wLf[10][256];
    __shared__ float vL[256], sc[160], red[2];

    const int tid = threadIdx.x;

    if (blockIdx.x >= 8) {
        int id = blockIdx.x - 8;                 // 0..239
        // ---------------- u16 GEMM tile (first 80 blocks) ----------------
        if (id < 80) {
            const int n0 = (id & 3) * 64, m0 = (id >> 2) * 64;
            const int tx = tid & 15, ty = (tid & 255) >> 4;
            float acc[4][4] = {};
            for (int k0 = 0; k0 < 256; k0 += 32) {
                if (tid < 256) {
#pragma unroll
                    for (int i = 0; i < 8; ++i) {
                        int e = tid + i * 256;
                        int kk = e & 31, m = e >> 5;
                        Xs[kk][m] = memory[(size_t)(m0 + m) * 256 + k0 + kk];
                        Ws2[kk][m] = Um[(size_t)(n0 + m) * 256 + k0 + kk];
                    }
                }
                __syncthreads();
                if (tid < 256) {
#pragma unroll
                    for (int kk = 0; kk < 32; ++kk) {
                        float a[4], b[4];
#pragma unroll
                        for (int i = 0; i < 4; ++i) a[i] = Xs[kk][ty * 4 + i];
#pragma unroll
                        for (int j = 0; j < 4; ++j) b[j] = Ws2[kk][tx * 4 + j];
#pragma unroll
                        for (int i = 0; i < 4; ++i)
#pragma unroll
                            for (int j = 0; j < 4; ++j) acc[i][j] += a[i] * b[j];
                    }
                }
                __syncthreads();
            }
            if (tid < 256) {
#pragma unroll
                for (int i = 0; i < 4; ++i)
#pragma unroll
                    for (int j = 0; j < 4; ++j)
                        u16[(size_t)(m0 + ty * 4 + i) * 256 + n0 + tx * 4 + j] =
                            (_Float16)acc[i][j];
            }
            if (!full) return;                   // fallback: u16 only
            __syncthreads();                     // drains all waves' stores
            if (tid == 0)
                __hip_atomic_fetch_add(&flags[8], 1, __ATOMIC_RELEASE,
                                       __HIP_MEMORY_SCOPE_AGENT);
        }
        if (!full) return;

        // ---------------- attention consumer (one chunk) -----------------
        const int grp = id / 30;                 // batch 0..7
        const int tc = id % 30;                  // t-chunk 0..29
        // wait all 80 u16 tiles: RELAXED poll (no cache inv), then one
        // ACQUIRE confirmation (single L1/L2 inv).
        if (tid == 0) {
            while (__hip_atomic_load(&flags[8], __ATOMIC_RELAXED,
                                     __HIP_MEMORY_SCOPE_AGENT) < 80)
                __builtin_amdgcn_s_sleep(32);
            while (__hip_atomic_load(&flags[8], __ATOMIC_ACQUIRE,
                                     __HIP_MEMORY_SCOPE_AGENT) < 80)
                __builtin_amdgcn_s_sleep(8);
        }
        __syncthreads();
        // stage uS for this batch (coalesced; padded rows -> conflict-free)
        const unsigned* ug = (const unsigned*)(u16 + (size_t)grp * 160 * 256);
        for (int i = tid; i < 20480; i += 512)
            uS[(i >> 7) * 129 + (i & 127)] = ug[i];
        if (tid < 256) vL[tid] = vv[tid];
        __syncthreads();

        // wait gru batch grp complete (single publish at step 300)
        if (tid == 0) {
            while (__hip_atomic_load(&flags[grp], __ATOMIC_RELAXED,
                                     __HIP_MEMORY_SCOPE_AGENT) < 1)
                __builtin_amdgcn_s_sleep(32);
            while (__hip_atomic_load(&flags[grp], __ATOMIC_ACQUIRE,
                                     __HIP_MEMORY_SCOPE_AGENT) < 1)
                __builtin_amdgcn_s_sleep(8);
        }
        __syncthreads();
        // stage the 10 outputs rows
        for (int i = tid; i < 2560; i += 512) {
            int ti = i >> 8, k = i & 255;
            oL[ti][k] = outs[((size_t)grp * 300 + tc * 10 + ti) * 256 + k];
        }
        __syncthreads();
        // w = rows @ W^T  (thread c owns column c; f32, exact old math)
        if (tid < 256) {
            float a0 = 0, a1 = 0, a2 = 0, a3 = 0, a4 = 0;
            float a5 = 0, a6 = 0, a7 = 0, a8 = 0, a9 = 0;
            for (int k4 = 0; k4 < 256; k4 += 4) {
                float4 wq = *(const float4*)(W + (size_t)tid * 256 + k4);
#define WROW(ACC, TI)                                                     \
                {                                                         \
                    float4 oq = *(const float4*)(&oL[TI][k4]);            \
                    ACC += wq.x * oq.x + wq.y * oq.y +                    \
                           wq.z * oq.z + wq.w * oq.w;                     \
                }
                WROW(a0, 0) WROW(a1, 1) WROW(a2, 2) WROW(a3, 3) WROW(a4, 4)
                WROW(a5, 5) WROW(a6, 6) WROW(a7, 7) WROW(a8, 8) WROW(a9, 9)
#undef WROW
            }
            wLf[0][tid] = a0; wLf[1][tid] = a1; wLf[2][tid] = a2;
            wLf[3][tid] = a3; wLf[4][tid] = a4; wLf[5][tid] = a5;
            wLf[6][tid] = a6; wLf[7][tid] = a7; wLf[8][tid] = a8;
            wLf[9][tid] = a9;
        }
        __syncthreads();
        // scores + softmax for the 10 rows (r6 attn code, wLf in LDS)
        for (int ti = 0; ti < 10; ++ti) {
            int t = tc * 10 + ti;
            float acc2 = 0.0f;
            if (tid < 160) {
                const unsigned* ur = uS + tid * 129;
                const float* wl = wLf[ti];
#pragma unroll 8
                for (int e2 = 0; e2 < 128; ++e2) {
                    union { unsigned uu2; _Float16 hh[2]; } cv;
                    cv.uu2 = ur[e2];
                    int ee = e2 * 2;
                    acc2 += vL[ee] * ftanh(wl[ee] + (float)cv.hh[0]);
                    acc2 += vL[ee + 1] * ftanh(wl[ee + 1] + (float)cv.hh[1]);
                }
                sc[tid] = acc2;
            }
            __syncthreads();
            if (tid < 64) {
                float m = -3.0e38f;
                for (int i = tid; i < 160; i += 64) m = fmaxf(m, sc[i]);
#pragma unroll
                for (int o = 32; o; o >>= 1) m = fmaxf(m, __shfl_xor(m, o));
                if (tid == 0) red[0] = m;
            }
            __syncthreads();
            float ee = 0.0f;
            if (tid < 160) {
                ee = fexp2((acc2 - red[0]) * 1.4426950408889634f);
                sc[tid] = ee;
            }
            __syncthreads();
            if (tid < 64) {
                float s = 0.0f;
                for (int i = tid; i < 160; i += 64) s += sc[i];
#pragma unroll
                for (int o = 32; o; o >>= 1) s += __shfl_xor(s, o);
                if (tid == 0) red[1] = s;
            }
            __syncthreads();
            if (tid < 160)
                attn[(size_t)(grp * 300 + t) * 160 + tid] = ee * frcp(red[1]);
            __syncthreads();
        }
        return;
    }

    // -------------------------- GRU path (exact r5 hot loop) -------------
    const int b = blockIdx.x;
    const int t = tid;
    const int w = t >> 6, l = t & 63;
    const int grp = l >> 4;
    const int sel = l & 7;
    const int hi = (l >> 3) & 1;
    const int m2s = sel >> 2, rsel = sel & 3;
    const int e = 32 * w + 16 * m2s + 4 * grp + rsel;

    f16x8 wf[48];
#pragma unroll
    for (int fi = 0; fi < 48; ++fi) {
        union { unsigned u[4]; f16x8 v; } cv;
#pragma unroll
        for (int j = 0; j < 4; ++j) cv.u[j] = wd[(fi * 4 + j) * 512 + t];
        wf[fi] = cv.v;
    }

    float h = h0[b * 256 + e];
    float bn = bhh[512 + e];
    if (!hi) hbuf[0][e] = (_Float16)h;
    const float* gp = gi + b * 768;
    float* op = outs + (size_t)b * 76800 + e;

    float gr = gp[e], gz = gp[e + 256], gn = gp[e + 512];
    __syncthreads();

    for (int st = 0; st < 300; ++st) {
        int stn = (st < 299) ? st + 1 : st;
        const float* g = gp + (size_t)stn * 6144;
        float grn = g[e], gzn = g[e + 256], gnn = g[e + 512];

        const _Float16* hb = hbuf[st & 1];
        f16x8 hv0 = *(const f16x8*)(hb + 0 * 32 + 8 * grp);
        f16x8 hv1 = *(const f16x8*)(hb + 1 * 32 + 8 * grp);
        f16x8 hv2 = *(const f16x8*)(hb + 2 * 32 + 8 * grp);
        f16x8 hv3 = *(const f16x8*)(hb + 3 * 32 + 8 * grp);
        f16x8 hv4 = *(const f16x8*)(hb + 4 * 32 + 8 * grp);
        f16x8 hv5 = *(const f16x8*)(hb + 5 * 32 + 8 * grp);
        f16x8 hv6 = *(const f16x8*)(hb + 6 * 32 + 8 * grp);
        f16x8 hv7 = *(const f16x8*)(hb + 7 * 32 + 8 * grp);

        f32x4 aR0 = {0.f, 0.f, 0.f, 0.f}, aR1 = {0.f, 0.f, 0.f, 0.f};
        f32x4 aZ0 = {0.f, 0.f, 0.f, 0.f}, aZ1 = {0.f, 0.f, 0.f, 0.f};
        f32x4 aN0 = {0.f, 0.f, 0.f, 0.f}, aN1 = {0.f, 0.f, 0.f, 0.f};
#define KSTEP(ks, hv)                                                        \
        aR0 = __builtin_amdgcn_mfma_f32_16x16x32_f16(wf[0 * 8 + ks], hv, aR0, 0, 0, 0); \
        aR1 = __builtin_amdgcn_mfma_f32_16x16x32_f16(wf[1 * 8 + ks], hv, aR1, 0, 0, 0); \
        aZ0 = __builtin_amdgcn_mfma_f32_16x16x32_f16(wf[2 * 8 + ks], hv, aZ0, 0, 0, 0); \
        aZ1 = __builtin_amdgcn_mfma_f32_16x16x32_f16(wf[3 * 8 + ks], hv, aZ1, 0, 0, 0); \
        aN0 = __builtin_amdgcn_mfma_f32_16x16x32_f16(wf[4 * 8 + ks], hv, aN0, 0, 0, 0); \
        aN1 = __builtin_amdgcn_mfma_f32_16x16x32_f16(wf[5 * 8 + ks], hv, aN1, 0, 0, 0);
        KSTEP(0, hv0) KSTEP(1, hv1) KSTEP(2, hv2) KSTEP(3, hv3)
        KSTEP(4, hv4) KSTEP(5, hv5) KSTEP(6, hv6) KSTEP(7, hv7)
#undef KSTEP

        f32x4 vR = m2s ? aR1 : aR0;
        f32x4 vZ = m2s ? aZ1 : aZ0;
        f32x4 vN = m2s ? aN1 : aN0;
        float sr = pick4(vR, rsel);
        float sz = pick4(vZ, rsel);
        float sn = pick4(vN, rsel);

        float r = fsig(gr + sr);
        float z = fsig(gz + sz);
        float n = ftanh(gn + r * (sn + bn));
        h = n + z * (h - n);

        gr = grn; gz = gzn; gn = gnn;

        if (hi)
            op[st * 256] = h;
        else
            hbuf[(st + 1) & 1][e] = (_Float16)h;
        asm volatile("s_waitcnt lgkmcnt(0)\n\ts_barrier" ::: "memory");
    }
    if (!hi) hid[b * 256 + e] = h;
    if (full) {
        // ONE publish: drain this wave's outs/hid stores, rendezvous, then a
        // single agent-RELEASE store (one buffer_wbl2 per block total).
        asm volatile("s_waitcnt vmcnt(0)" ::: "memory");
        __syncthreads();
        if (t == 0)
            __hip_atomic_store(&flags[b], 1, __ATOMIC_RELEASE,
                               __HIP_MEMORY_SCOPE_AGENT);
    }
}

// ---------------------------------------------------------------------------
// Kernel D (FALLBACK only): r6 attn kernel (reads precomputed wv).
// ---------------------------------------------------------------------------
__global__ __launch_bounds__(256) void attn_kernel(
    const _Float16* __restrict__ u16, const float* __restrict__ wv,
    const float* __restrict__ v, float* __restrict__ attn) {
    const int tc = blockIdx.x, b = blockIdx.y;
    const int tid = threadIdx.x;
    __shared__ float wL[256], vL[256], sc[160], red[2];
    __shared__ unsigned uS[160 * 129];

    const unsigned* ug = (const unsigned*)(u16 + (size_t)b * 160 * 256);
    for (int i = tid; i < 20480; i += 256)
        uS[(i >> 7) * 129 + (i & 127)] = ug[i];
    vL[tid] = v[tid];

    for (int ti = 0; ti < 10; ++ti) {
        int t = tc * 10 + ti;
        wL[tid] = wv[(size_t)(b * 300 + t) * 256 + tid];
        __syncthreads();
        float acc = 0.0f;
        if (tid < 160) {
            const unsigned* ur = uS + tid * 129;
#pragma unroll 8
            for (int e2 = 0; e2 < 128; ++e2) {
                union { unsigned uu; _Float16 hh[2]; } cv;
                cv.uu = ur[e2];
                int ee = e2 * 2;
                acc += vL[ee] * ftanh(wL[ee] + (float)cv.hh[0]);
                acc += vL[ee + 1] * ftanh(wL[ee + 1] + (float)cv.hh[1]);
            }
            sc[tid] = acc;
        }
        __syncthreads();
        if (tid < 64) {
            float m = -3.0e38f;
            for (int i = tid; i < 160; i += 64) m = fmaxf(m, sc[i]);
#pragma unroll
            for (int o = 32; o; o >>= 1) m = fmaxf(m, __shfl_xor(m, o));
            if (tid == 0) red[0] = m;
        }
        __syncthreads();
        float ee = 0.0f;
        if (tid < 160) {
            ee = fexp2((acc - red[0]) * 1.4426950408889634f);
            sc[tid] = ee;
        }
        __syncthreads();
        if (tid < 64) {
            float s = 0.0f;
            for (int i = tid; i < 160; i += 64) s += sc[i];
#pragma unroll
            for (int o = 32; o; o >>= 1) s += __shfl_xor(s, o);
            if (tid == 0) red[1] = s;
        }
        __syncthreads();
        if (tid < 160)
            attn[(size_t)(b * 300 + t) * 160 + tid] = ee * frcp(red[1]);
        __syncthreads();
    }
}

// ---------------------------------------------------------------------------
// ws layout (bytes):
//   [0, 7372800)        gi f32 [(t*8+b)*768 + col]
//   [7372800, 7766016)  wd u32 mfma A-frags [i*512+t]
//   [7766016, 8421376)  u16 f16 [b*160+x][256]   (full path)
//   [8421376, 8421416)  flags: prog[8], u16done  (full path)
//   fallback: u16 at ws+0, wbuf at ws+655360 (post-gru aliasing, as r5)
// ---------------------------------------------------------------------------
extern "C" void kernel_launch(void* const* d_in, const int* in_sizes, int n_in,
                              void* d_out, int out_size, void* d_ws, size_t ws_size,
                              hipStream_t stream) {
    const float* inputs = (const float*)d_in[0];
    const float* memory = (const float*)d_in[1];
    const float* h0 = (const float*)d_in[2];
    const float* Wih = (const float*)d_in[3];
    const float* Whh = (const float*)d_in[4];
    const float* bih = (const float*)d_in[5];
    const float* bhh = (const float*)d_in[6];
    const float* Wm = (const float*)d_in[7];
    const float* Um = (const float*)d_in[8];
    const float* vv = (const float*)d_in[9];

    float* out = (float*)d_out;
    float* out_attn = out;              // 384000
    float* out_outputs = out + 384000;  // 614400
    float* out_hidden = out + 998400;   // 2048

    char* ws = (char*)d_ws;
    float* gi = (float*)ws;
    unsigned* wd = (unsigned*)(ws + 7372800);

    const size_t U16_OFF = 7766016, FLAG_OFF = 8421376;
    const bool full = ws_size >= FLAG_OFF + 64;
    _Float16* u16 = full ? (_Float16*)(ws + U16_OFF) : (_Float16*)ws;
    int* flags = (int*)(ws + FLAG_OFF);

    // Phase 1: weight repack + gi GEMM + flag zeroing (one launch).
    phase1_kernel<<<840, 256, 0, stream>>>(Whh, wd, inputs, Wih, gi, bih, bhh,
                                           flags, full ? 1 : 0);
    if (full) {
        // Phase 2: GRU + u16 GEMM + overlapped w/attention consumers.
        gru_mega<<<248, 512, 0, stream>>>(gi, wd, h0, bhh, out_outputs,
                                          out_hidden, memory, Um, u16, Wm, vv,
                                          out_attn, flags, 1);
    } else {
        // Fallback: r5-style serial pipeline.
        float* wbuf = (float*)(ws + 655360);
        gru_mega<<<8, 512, 0, stream>>>(gi, wd, h0, bhh, out_outputs,
                                        out_hidden, memory, Um, u16, Wm, vv,
                                        out_attn, flags, 0);
        gemm_kernel<<<dim3(4, 20), 256, 0, stream>>>(memory, Um, nullptr, u16,
                                                     1280, 256, 256, 2);
        gemm_kernel<<<dim3(4, 38), 256, 0, stream>>>(out_outputs, Wm, wbuf,
                                                     nullptr, 2400, 256, 256, 0);
        attn_kernel<<<dim3(30, 8), 256, 0, stream>>>(u16, wbuf, vv, out_attn);
    }
}